// Round 9
// baseline (1742.100 us; speedup 1.0000x reference)
//
#include <hip/hip_runtime.h>
#include <hip/hip_bf16.h>

#define NB 16
#define NN 2048
#define KNNK 16
#define MM 1024
#define RC1 (NB*NN*KNNK)   // 524288 conv1 BN rows
#define RC2 (NB*MM*KNNK)   // 262144 conv2 BN rows

typedef unsigned long long u64;
typedef __attribute__((ext_vector_type(8))) short short8;
typedef __attribute__((ext_vector_type(4))) float f32x4;

__device__ __forceinline__ float frn_mul(float a, float b){ return __fmul_rn(a,b); }
__device__ __forceinline__ float frn_add(float a, float b){ return __fadd_rn(a,b); }
__device__ __forceinline__ float frn_sub(float a, float b){ return __fsub_rn(a,b); }
__device__ __forceinline__ float silu_f(float x){ return x / (1.0f + __expf(-x)); }
__device__ __forceinline__ u64 umax64(u64 a, u64 b){ return a > b ? a : b; }

__device__ __forceinline__ unsigned f32_sortable(float f){
  unsigned u = __float_as_uint(f);
  return u ^ ((unsigned)((int)u >> 31) | 0x80000000u);
}
__device__ __forceinline__ unsigned short f2bf(float f){
  unsigned u = __float_as_uint(f);
  return (unsigned short)((u + 0x7FFFu + ((u >> 16) & 1u)) >> 16);
}
__device__ __forceinline__ float bf2f(unsigned short h){
  return __uint_as_float(((unsigned)h) << 16);
}

__device__ __forceinline__ void atomicMaxF(unsigned* addr, float v){
  if (v >= 0.f) atomicMax((int*)addr, (int)__float_as_uint(v));
  else          atomicMin(addr, __float_as_uint(v));
}
__device__ __forceinline__ void atomicMinF(unsigned* addr, float v){
  if (v >= 0.f) atomicMin((int*)addr, (int)__float_as_uint(v));
  else          atomicMax(addr, __float_as_uint(v));
}

__global__ __launch_bounds__(256) void init_kernel(float* stats1, float* stats2a, float* stats2b,
                                                   unsigned* gmax, unsigned* gmin){
  int t = blockIdx.x*256 + threadIdx.x;
  if (t < 128) stats1[t] = 0.f;
  if (t < 256) stats2a[t] = 0.f;
  if (t < 512) stats2b[t] = 0.f;
  if (t < 4096){ gmax[t] = 0xFF800000u; gmin[t] = 0x7F800000u; }
}

// ---- K0: blocks 0..15 = FPS (r7-proven), blocks 16..143 = fused knn1 + conv1 stats ----
__global__ __launch_bounds__(256) void k0_mega(const float* __restrict__ pos,
    int* __restrict__ idxf, float* __restrict__ pos2, int* __restrict__ idx1,
    const float* __restrict__ W1, const float* __restrict__ b1, float* __restrict__ stats1){
  __shared__ __align__(16) char smem[51*1024];
  int tid = threadIdx.x;
  if (blockIdx.x < 16){
    int b = blockIdx.x;
    float4* pts4 = (float4*)smem;                    // 2048 * 16B = 32 KB
    int* sel = (int*)(smem + 32*1024);               // 1024 ints
    u64* wred = (u64*)(smem + 36*1024);              // [2][4]
    const float* pb = pos + (size_t)b*NN*3;
    float X[8], Y[8], Z[8], MD[8];
    unsigned LO[8];
#pragma unroll
    for (int q = 0; q < 8; ++q){
      int p = tid + 256*q;
      float x = pb[p*3+0], y = pb[p*3+1], z = pb[p*3+2];
      X[q] = x; Y[q] = y; Z[q] = z;
      LO[q] = ~(unsigned)p;
      pts4[p] = make_float4(x, y, z, 0.f);
    }
    float qx = pb[0], qy = pb[1], qz = pb[2];
#pragma unroll
    for (int q = 0; q < 8; ++q){
      float dx = frn_sub(X[q],qx), dy = frn_sub(Y[q],qy), dz = frn_sub(Z[q],qz);
      MD[q] = frn_add(frn_add(frn_mul(dx,dx), frn_mul(dy,dy)), frn_mul(dz,dz));
    }
    if (tid == 0) sel[0] = 0;
    int wv = tid >> 6;
    __syncthreads();
    for (int s = 1; s < MM; ++s){
      u64 t0 = umax64(((u64)__float_as_uint(MD[0])<<32)|LO[0], ((u64)__float_as_uint(MD[1])<<32)|LO[1]);
      u64 t1 = umax64(((u64)__float_as_uint(MD[2])<<32)|LO[2], ((u64)__float_as_uint(MD[3])<<32)|LO[3]);
      u64 t2 = umax64(((u64)__float_as_uint(MD[4])<<32)|LO[4], ((u64)__float_as_uint(MD[5])<<32)|LO[5]);
      u64 t3 = umax64(((u64)__float_as_uint(MD[6])<<32)|LO[6], ((u64)__float_as_uint(MD[7])<<32)|LO[7]);
      u64 kk = umax64(umax64(t0, t1), umax64(t2, t3));
#define RED_DPP(CTRL) { \
      unsigned lo_ = (unsigned)kk, hi_ = (unsigned)(kk>>32); \
      unsigned plo = (unsigned)__builtin_amdgcn_update_dpp((int)lo_,(int)lo_,CTRL,0xF,0xF,false); \
      unsigned phi = (unsigned)__builtin_amdgcn_update_dpp((int)hi_,(int)hi_,CTRL,0xF,0xF,false); \
      u64 o = ((u64)phi<<32)|plo; kk = o > kk ? o : kk; }
      RED_DPP(0xB1)
      RED_DPP(0x4E)
      RED_DPP(0x124)
      RED_DPP(0x128)
      RED_DPP(0x142)
      RED_DPP(0x143)
#undef RED_DPP
      int par = s & 1;
      if ((tid & 63) == 63) wred[par*4 + wv] = kk;
      __syncthreads();
      const u64* wr = wred + par*4;
      u64 K = umax64(umax64(wr[0], wr[1]), umax64(wr[2], wr[3]));
      unsigned wp = ~(unsigned)K;
      if (tid == 0) sel[s] = (int)wp;
      float4 wc = pts4[wp];
#pragma unroll
      for (int q = 0; q < 8; ++q){
        float dx = frn_sub(X[q],wc.x), dy = frn_sub(Y[q],wc.y), dz = frn_sub(Z[q],wc.z);
        float d = frn_add(frn_add(frn_mul(dx,dx), frn_mul(dy,dy)), frn_mul(dz,dz));
        MD[q] = fminf(MD[q], d);
      }
    }
    __syncthreads();
    for (int m = tid; m < MM; m += 256){
      int j = sel[m];
      idxf[b*MM + m] = j;
      float4 c = pts4[j];
      pos2[(size_t)(b*MM+m)*3+0] = c.x;
      pos2[(size_t)(b*MM+m)*3+1] = c.y;
      pos2[(size_t)(b*MM+m)*3+2] = c.z;
    }
  } else {
    // fused knn1 (full 2048-point row) + conv1 stats
    int cid = blockIdx.x - 16;                  // 0..127
    int b = cid >> 3, rblk = cid & 7;
    float4* pts4 = (float4*)smem;               // 2048 pts (x,y,z,n2) = 32 KB
    int* idxl = (int*)(smem + 32*1024);         // 256 rows x 16 = 16 KB
    float* red = (float*)(smem + 48*1024);      // 4*64*2 floats = 2 KB
    const float* pb = pos + (size_t)b*NN*3;
    for (int i = tid; i < NN; i += 256){
      float x = pb[i*3+0], y = pb[i*3+1], z = pb[i*3+2];
      float n2 = frn_add(frn_add(frn_mul(x,x), frn_mul(y,y)), frn_mul(z,z));
      pts4[i] = make_float4(x, y, z, n2);
    }
    __syncthreads();
    int i = rblk*256 + tid;
    float4 qv = pts4[i];
    float xi = qv.x, yi = qv.y, zi = qv.z, n2i = qv.w;
    u64 best[KNNK];
#pragma unroll
    for (int p = 0; p < KNNK; ++p) best[p] = ~0ull;
    for (int jj = 0; jj < NN; ++jj){
      float4 v = pts4[jj];
      float e = frn_add(frn_add(frn_mul(xi,v.x), frn_mul(yi,v.y)), frn_mul(zi,v.z));
      float d = frn_sub(frn_add(n2i, v.w), frn_mul(2.0f, e));
      u64 key = ((u64)f32_sortable(d) << 32) | (unsigned)jj;
      if (key < best[KNNK-1]){
        u64 cur = key;
#pragma unroll
        for (int p = 0; p < KNNK; ++p){
          u64 mn = best[p] < cur ? best[p] : cur;
          u64 mx = best[p] < cur ? cur : best[p];
          best[p] = mn; cur = mx;
        }
      }
    }
    int* op = idx1 + ((size_t)(b*NN + i))*KNNK;
#pragma unroll
    for (int p = 0; p < KNNK; ++p){
      int j = (int)(unsigned)(best[p] & 0xFFFFFFFFull);
      op[p] = j;
      idxl[tid*KNNK + p] = j;
    }
    __syncthreads();
    // conv1 stats: wave per row, 64 rows per wave, all data from LDS
    int lane = tid & 63, wv = tid >> 6;
    float w[6];
#pragma unroll
    for (int f = 0; f < 6; ++f) w[f] = W1[f*64 + lane];
    float bias = b1[lane];
    float ssum = 0.f, ssq = 0.f;
    for (int r = 0; r < 64; ++r){
      int lrow = wv*64 + r;
      float4 pi = pts4[rblk*256 + lrow];
      const int* ip = idxl + lrow*KNNK;
#pragma unroll 4
      for (int k = 0; k < KNNK; ++k){
        int j = ip[k];
        float4 pj = pts4[j];
        float y = bias;
        y = fmaf(pj.x, w[0], y); y = fmaf(pj.y, w[1], y); y = fmaf(pj.z, w[2], y);
        y = fmaf(pj.x - pi.x, w[3], y); y = fmaf(pj.y - pi.y, w[4], y); y = fmaf(pj.z - pi.z, w[5], y);
        ssum += y; ssq = fmaf(y, y, ssq);
      }
    }
    red[(wv*64+lane)*2+0] = ssum; red[(wv*64+lane)*2+1] = ssq;
    __syncthreads();
    if (tid < 64){
      float s = red[(0*64+lane)*2]+red[(1*64+lane)*2]+red[(2*64+lane)*2]+red[(3*64+lane)*2];
      float q = red[(0*64+lane)*2+1]+red[(1*64+lane)*2+1]+red[(2*64+lane)*2+1]+red[(3*64+lane)*2+1];
      atomicAdd(&stats1[lane], s);
      atomicAdd(&stats1[64+lane], q);
    }
  }
}

// ---- K1: blocks 0..63 = knn2 (full 1024-pt rows), blocks 64..1087 = conv1 apply ----
__global__ __launch_bounds__(256) void k1_knn2_c1apply(
    const float* __restrict__ pos2, int* __restrict__ idx2,
    const float* __restrict__ pos, const int* __restrict__ idx1,
    const float* __restrict__ W1, const float* __restrict__ b1,
    const float* __restrict__ g1, const float* __restrict__ be1,
    const float* __restrict__ stats1, float* __restrict__ h){
  __shared__ __align__(16) float4 sm[1024];
  int tid = threadIdx.x;
  if (blockIdx.x < 64){
    int b = blockIdx.x >> 2, rblk = blockIdx.x & 3;
    const float* pb = pos2 + (size_t)b*MM*3;
    for (int t = tid; t < MM; t += 256){
      float x = pb[t*3+0], y = pb[t*3+1], z = pb[t*3+2];
      float n2 = frn_add(frn_add(frn_mul(x,x), frn_mul(y,y)), frn_mul(z,z));
      sm[t] = make_float4(x, y, z, n2);
    }
    __syncthreads();
    int i = rblk*256 + tid;
    float4 qv = sm[i];
    float xi = qv.x, yi = qv.y, zi = qv.z, n2i = qv.w;
    u64 best[KNNK];
#pragma unroll
    for (int p = 0; p < KNNK; ++p) best[p] = ~0ull;
    for (int jj = 0; jj < MM; ++jj){
      float4 v = sm[jj];
      float e = frn_add(frn_add(frn_mul(xi,v.x), frn_mul(yi,v.y)), frn_mul(zi,v.z));
      float d = frn_sub(frn_add(n2i, v.w), frn_mul(2.0f, e));
      u64 key = ((u64)f32_sortable(d) << 32) | (unsigned)jj;
      if (key < best[KNNK-1]){
        u64 cur = key;
#pragma unroll
        for (int p = 0; p < KNNK; ++p){
          u64 mn = best[p] < cur ? best[p] : cur;
          u64 mx = best[p] < cur ? cur : best[p];
          best[p] = mn; cur = mx;
        }
      }
    }
    int* op = idx2 + ((size_t)(b*MM + i))*KNNK;
#pragma unroll
    for (int p = 0; p < KNNK; ++p) op[p] = (int)(unsigned)(best[p] & 0xFFFFFFFFull);
  } else {
    int lane = tid & 63, wv = tid >> 6;
    int wave = (blockIdx.x - 64)*4 + wv;
    float w[6];
#pragma unroll
    for (int f = 0; f < 6; ++f) w[f] = W1[f*64 + lane];
    float bias = b1[lane];
    const float inv = 1.0f / (float)RC1;
    float mu = stats1[lane] * inv;
    float var = fmaxf(stats1[64+lane]*inv - mu*mu, 0.f);
    float sc = rsqrtf(var + 1e-5f) * g1[lane];
    float sh = be1[lane] - mu*sc;
    for (int r = 0; r < 8; ++r){
      int row = wave*8 + r;
      int b = row >> 11, ii = row & 2047;
      const float* pi = pos + ((size_t)(b*NN + ii))*3;
      float xi = pi[0], yi = pi[1], zi = pi[2];
      const int* ip = idx1 + (size_t)row * KNNK;
      float ymn = INFINITY, ymx = -INFINITY;
#pragma unroll 4
      for (int k = 0; k < KNNK; ++k){
        int j = ip[k];
        const float* pj = pos + ((size_t)(b*NN + j))*3;
        float xj = pj[0], yj = pj[1], zj = pj[2];
        float y = bias;
        y = fmaf(xj, w[0], y); y = fmaf(yj, w[1], y); y = fmaf(zj, w[2], y);
        y = fmaf(xj - xi, w[3], y); y = fmaf(yj - yi, w[4], y); y = fmaf(zj - zi, w[5], y);
        ymn = fminf(ymn, y); ymx = fmaxf(ymx, y);
      }
      h[((size_t)row << 6) + lane] = fmaxf(silu_f(fmaf(ymx, sc, sh)), silu_f(fmaf(ymn, sc, sh)));
    }
  }
}

// ---- conv2a: 4 rows share each LDS weight read (r7-proven) ----
__global__ __launch_bounds__(256) void conv2a_kernel(
    const float* __restrict__ h, const int* __restrict__ idxf,
    const float* __restrict__ pos2, const int* __restrict__ idx2,
    const float* __restrict__ W2a, const float* __restrict__ b2a,
    float* __restrict__ stats2a, __hip_bfloat16* __restrict__ y2a){
  __shared__ float Wl[67*128];
  __shared__ float red[4][64][4];
  for (int t = threadIdx.x; t < 67*128; t += 256) Wl[t] = W2a[t];
  __syncthreads();
  int lane = threadIdx.x & 63, wv = threadIdx.x >> 6;
  int wave = blockIdx.x*4 + wv;                 // 0..4095, 64 rows each
  float bias0 = b2a[lane], bias1 = b2a[64+lane];
  float ssum0=0, ssq0=0, ssum1=0, ssq1=0;
  for (int r4 = 0; r4 < 16; ++r4){
    int row0 = wave*64 + r4*4;
    int b = row0 >> 14;
    int m = (row0 >> 4) & 1023;
    int j0 = idx2[row0+0], j1 = idx2[row0+1], j2 = idx2[row0+2], j3 = idx2[row0+3];
    int q0 = idxf[b*MM + j0], q1 = idxf[b*MM + j1], q2 = idxf[b*MM + j2], q3 = idxf[b*MM + j3];
    const float4* h0 = (const float4*)(h + ((size_t)(b*NN + q0) << 6));
    const float4* h1 = (const float4*)(h + ((size_t)(b*NN + q1) << 6));
    const float4* h2 = (const float4*)(h + ((size_t)(b*NN + q2) << 6));
    const float4* h3 = (const float4*)(h + ((size_t)(b*NN + q3) << 6));
    float y00=bias0, y01=bias1, y10=bias0, y11=bias1;
    float y20=bias0, y21=bias1, y30=bias0, y31=bias1;
#define C2A_STEP(e, a0v, a1v, a2v, a3v) { \
      float w0_ = Wl[(e)*128 + lane], w1_ = Wl[(e)*128 + 64 + lane]; \
      y00 = fmaf(a0v, w0_, y00); y01 = fmaf(a0v, w1_, y01); \
      y10 = fmaf(a1v, w0_, y10); y11 = fmaf(a1v, w1_, y11); \
      y20 = fmaf(a2v, w0_, y20); y21 = fmaf(a2v, w1_, y21); \
      y30 = fmaf(a3v, w0_, y30); y31 = fmaf(a3v, w1_, y31); }
#pragma unroll
    for (int f4 = 0; f4 < 16; ++f4){
      float4 v0 = h0[f4], v1 = h1[f4], v2 = h2[f4], v3 = h3[f4];
      C2A_STEP(f4*4+0, v0.x, v1.x, v2.x, v3.x)
      C2A_STEP(f4*4+1, v0.y, v1.y, v2.y, v3.y)
      C2A_STEP(f4*4+2, v0.z, v1.z, v2.z, v3.z)
      C2A_STEP(f4*4+3, v0.w, v1.w, v2.w, v3.w)
    }
    const float* pm = pos2 + ((size_t)(b*MM + m))*3;
    float pmx = pm[0], pmy = pm[1], pmz = pm[2];
    const float* pj0 = pos2 + ((size_t)(b*MM + j0))*3;
    const float* pj1 = pos2 + ((size_t)(b*MM + j1))*3;
    const float* pj2 = pos2 + ((size_t)(b*MM + j2))*3;
    const float* pj3 = pos2 + ((size_t)(b*MM + j3))*3;
    C2A_STEP(64, pj0[0]-pmx, pj1[0]-pmx, pj2[0]-pmx, pj3[0]-pmx)
    C2A_STEP(65, pj0[1]-pmy, pj1[1]-pmy, pj2[1]-pmy, pj3[1]-pmy)
    C2A_STEP(66, pj0[2]-pmz, pj1[2]-pmz, pj2[2]-pmz, pj3[2]-pmz)
#undef C2A_STEP
    ssum0 += y00+y10+y20+y30;
    ssum1 += y01+y11+y21+y31;
    ssq0 = fmaf(y00,y00,fmaf(y10,y10,fmaf(y20,y20,fmaf(y30,y30,ssq0))));
    ssq1 = fmaf(y01,y01,fmaf(y11,y11,fmaf(y21,y21,fmaf(y31,y31,ssq1))));
    y2a[(size_t)(row0+0)*128 + lane]      = __float2bfloat16(y00);
    y2a[(size_t)(row0+0)*128 + 64 + lane] = __float2bfloat16(y01);
    y2a[(size_t)(row0+1)*128 + lane]      = __float2bfloat16(y10);
    y2a[(size_t)(row0+1)*128 + 64 + lane] = __float2bfloat16(y11);
    y2a[(size_t)(row0+2)*128 + lane]      = __float2bfloat16(y20);
    y2a[(size_t)(row0+2)*128 + 64 + lane] = __float2bfloat16(y21);
    y2a[(size_t)(row0+3)*128 + lane]      = __float2bfloat16(y30);
    y2a[(size_t)(row0+3)*128 + 64 + lane] = __float2bfloat16(y31);
  }
  red[wv][lane][0]=ssum0; red[wv][lane][1]=ssq0; red[wv][lane][2]=ssum1; red[wv][lane][3]=ssq1;
  __syncthreads();
  if (threadIdx.x < 64){
    float s0=0,q0=0,s1=0,q1=0;
#pragma unroll
    for (int v2=0; v2<4; ++v2){ s0+=red[v2][lane][0]; q0+=red[v2][lane][1]; s1+=red[v2][lane][2]; q1+=red[v2][lane][3]; }
    atomicAdd(&stats2a[lane], s0);      atomicAdd(&stats2a[128+lane], q0);
    atomicAdd(&stats2a[64+lane], s1);   atomicAdd(&stats2a[192+lane], q1);
  }
}

// ---- conv2b: MFMA 16x16x32 bf16 (r7-proven) ----
__global__ __launch_bounds__(256) void conv2b_kernel(
    const __hip_bfloat16* __restrict__ y2a, const float* __restrict__ stats2a,
    const float* __restrict__ g2a, const float* __restrict__ be2a,
    const float* __restrict__ W2b, const float* __restrict__ b2b,
    float* __restrict__ stats2b, unsigned* __restrict__ gmax, unsigned* __restrict__ gmin){
  __shared__ __align__(16) char Albs[64*256];
  __shared__ __align__(16) char Btbs[64*256];
  __shared__ float sc2a[128], sh2a[128];
  int tid = threadIdx.x;
  int lane = tid & 63, wvi = tid >> 6;
  int ct = blockIdx.x & 3;
  int rb = blockIdx.x >> 2;
  int c0 = ct * 64;
  int batch = rb >> 5;
  if (tid < 128){
    const float inv = 1.0f / (float)RC2;
    float mu = stats2a[tid] * inv;
    float var = fmaxf(stats2a[128+tid]*inv - mu*mu, 0.f);
    float s = rsqrtf(var + 1e-5f) * g2a[tid];
    sc2a[tid] = s; sh2a[tid] = be2a[tid] - mu*s;
  }
  {
    int cc = tid & 63, u0 = tid >> 6;
#pragma unroll
    for (int i = 0; i < 4; ++i){
      int u = u0 + i*4;
      unsigned short hb[8];
#pragma unroll
      for (int e = 0; e < 8; ++e) hb[e] = f2bf(W2b[(size_t)(u*8+e)*256 + c0 + cc]);
      *(short8*)(Btbs + cc*256 + u*16) = *(short8*)hb;
    }
  }
  __syncthreads();
  short8 bfrag[4];
#pragma unroll
  for (int kb4 = 0; kb4 < 4; ++kb4){
    int col_local = wvi*16 + (lane & 15);
    bfrag[kb4] = *(short8*)(Btbs + col_local*256 + kb4*64 + (lane>>4)*16);
  }
  float bb = b2b[c0 + wvi*16 + (lane & 15)];
  float vmn = INFINITY, vmx = -INFINITY, ssum = 0.f, ssq = 0.f;
  const unsigned short* y2u = (const unsigned short*)y2a;
  int sr = tid & 63, su = tid >> 6;
  for (int tile = 0; tile < 8; ++tile){
    int row0 = rb*512 + tile*64;
    if (tile > 0) __syncthreads();
#pragma unroll
    for (int i = 0; i < 4; ++i){
      int u = su + i*4;
      short8 v = *(const short8*)(y2u + (size_t)(row0 + sr)*128 + u*8);
      unsigned short ha[8];
#pragma unroll
      for (int e = 0; e < 8; ++e){
        int k = u*8 + e;
        float f = bf2f((unsigned short)v[e]);
        ha[e] = f2bf(silu_f(fmaf(f, sc2a[k], sh2a[k])));
      }
      *(short8*)(Albs + sr*256 + ((u*16) ^ ((sr & 7) << 4))) = *(short8*)ha;
    }
    __syncthreads();
#pragma unroll
    for (int sl = 0; sl < 4; ++sl){
      f32x4 acc = {0.f, 0.f, 0.f, 0.f};
#pragma unroll
      for (int kb4 = 0; kb4 < 4; ++kb4){
        int r = sl*16 + (lane & 15);
        short8 afrag = *(short8*)(Albs + r*256 + ((kb4*64 + (lane>>4)*16) ^ ((r & 7) << 4)));
        acc = __builtin_amdgcn_mfma_f32_16x16x32_bf16(afrag, bfrag[kb4], acc, 0, 0, 0);
      }
#pragma unroll
      for (int j = 0; j < 4; ++j){
        float y = acc[j] + bb;
        vmn = fminf(vmn, y); vmx = fmaxf(vmx, y);
        ssum += y; ssq = fmaf(y, y, ssq);
      }
    }
  }
#pragma unroll
  for (int off = 16; off <= 32; off += 16){
    vmn  = fminf(vmn,  __shfl_xor(vmn,  off));
    vmx  = fmaxf(vmx,  __shfl_xor(vmx,  off));
    ssum = ssum + __shfl_xor(ssum, off);
    ssq  = ssq  + __shfl_xor(ssq,  off);
  }
  if ((lane >> 4) == 0){
    int c = c0 + wvi*16 + lane;
    atomicAdd(&stats2b[c], ssum);
    atomicAdd(&stats2b[256+c], ssq);
    atomicMaxF(&gmax[batch*256 + c], vmx);
    atomicMinF(&gmin[batch*256 + c], vmn);
  }
}

__global__ __launch_bounds__(256) void final_kernel(
    const float* __restrict__ stats2b, const unsigned* __restrict__ gmax,
    const unsigned* __restrict__ gmin, const float* __restrict__ g2b,
    const float* __restrict__ be2b, float* __restrict__ out){
  int t = blockIdx.x*256 + threadIdx.x;
  if (t >= NB*256) return;
  int c = t & 255;
  const float inv = 1.0f / (float)RC2;
  float mu = stats2b[c]*inv;
  float var = fmaxf(stats2b[256+c]*inv - mu*mu, 0.f);
  float sc = rsqrtf(var + 1e-5f)*g2b[c];
  float sh = be2b[c] - mu*sc;
  float mx = __uint_as_float(gmax[t]);
  float mn = __uint_as_float(gmin[t]);
  out[t] = fmaxf(silu_f(fmaf(mx, sc, sh)), silu_f(fmaf(mn, sc, sh)));
}

extern "C" void kernel_launch(void* const* d_in, const int* in_sizes, int n_in,
                              void* d_out, int out_size, void* d_ws, size_t ws_size,
                              hipStream_t stream){
  (void)in_sizes; (void)n_in; (void)out_size; (void)ws_size;
  const float* pos  = (const float*)d_in[0];
  const float* W1   = (const float*)d_in[1];
  const float* b1   = (const float*)d_in[2];
  const float* g1   = (const float*)d_in[3];
  const float* be1  = (const float*)d_in[4];
  const float* W2a  = (const float*)d_in[5];
  const float* b2a  = (const float*)d_in[6];
  const float* g2a  = (const float*)d_in[7];
  const float* be2a = (const float*)d_in[8];
  const float* W2b  = (const float*)d_in[9];
  const float* b2b  = (const float*)d_in[10];
  const float* g2b  = (const float*)d_in[11];
  const float* be2b = (const float*)d_in[12];

  char* w = (char*)d_ws;
  size_t off = 0;
  auto carve = [&](size_t bytes)->void*{ void* p = w + off; off += (bytes + 255) & ~(size_t)255; return p; };
  int*      idx1    = (int*)carve((size_t)NB*NN*KNNK*4);      // 2 MB
  float*    h       = (float*)carve((size_t)NB*NN*64*4);      // 8 MB
  int*      idxf    = (int*)carve((size_t)NB*MM*4);
  float*    pos2    = (float*)carve((size_t)NB*MM*3*4);
  int*      idx2    = (int*)carve((size_t)NB*MM*KNNK*4);      // 1 MB
  float*    stats1  = (float*)carve(128*4);
  float*    stats2a = (float*)carve(256*4);
  float*    stats2b = (float*)carve(512*4);
  unsigned* gmax    = (unsigned*)carve(4096*4);
  unsigned* gmin    = (unsigned*)carve(4096*4);
  __hip_bfloat16* y2a = (__hip_bfloat16*)carve((size_t)RC2*128*2);  // 64 MB

  init_kernel<<<dim3(16), dim3(256), 0, stream>>>(stats1, stats2a, stats2b, gmax, gmin);
  k0_mega<<<dim3(144), dim3(256), 0, stream>>>(pos, idxf, pos2, idx1, W1, b1, stats1);
  k1_knn2_c1apply<<<dim3(1088), dim3(256), 0, stream>>>(pos2, idx2, pos, idx1, W1, b1, g1, be1, stats1, h);
  conv2a_kernel<<<dim3(1024), dim3(256), 0, stream>>>(h, idxf, pos2, idx2, W2a, b2a, stats2a, y2a);
  conv2b_kernel<<<dim3(2048), dim3(256), 0, stream>>>(y2a, stats2a, g2a, be2a, W2b, b2b, stats2b, gmax, gmin);
  final_kernel<<<dim3(16), dim3(256), 0, stream>>>(stats2b, gmax, gmin, g2b, be2b, (float*)d_out);
}

// Round 10
// 1254.745 us; speedup vs baseline: 1.3884x; 1.3884x over previous
//
#include <hip/hip_runtime.h>
#include <hip/hip_bf16.h>

#define NB 16
#define NN 2048
#define KNNK 16
#define MM 1024
#define RC1 (NB*NN*KNNK)   // 524288 conv1 BN rows
#define RC2 (NB*MM*KNNK)   // 262144 conv2 BN rows

typedef unsigned long long u64;
typedef __attribute__((ext_vector_type(8))) short short8;
typedef __attribute__((ext_vector_type(4))) float f32x4;

__device__ __forceinline__ float frn_mul(float a, float b){ return __fmul_rn(a,b); }
__device__ __forceinline__ float frn_add(float a, float b){ return __fadd_rn(a,b); }
__device__ __forceinline__ float frn_sub(float a, float b){ return __fsub_rn(a,b); }
__device__ __forceinline__ float silu_f(float x){ return x / (1.0f + __expf(-x)); }
__device__ __forceinline__ u64 umax64(u64 a, u64 b){ return a > b ? a : b; }

__device__ __forceinline__ unsigned f32_sortable(float f){
  unsigned u = __float_as_uint(f);
  return u ^ ((unsigned)((int)u >> 31) | 0x80000000u);
}
__device__ __forceinline__ unsigned short f2bf(float f){
  unsigned u = __float_as_uint(f);
  return (unsigned short)((u + 0x7FFFu + ((u >> 16) & 1u)) >> 16);
}
__device__ __forceinline__ float bf2f(unsigned short h){
  return __uint_as_float(((unsigned)h) << 16);
}

__device__ __forceinline__ void atomicMaxF(unsigned* addr, float v){
  if (v >= 0.f) atomicMax((int*)addr, (int)__float_as_uint(v));
  else          atomicMin(addr, __float_as_uint(v));
}
__device__ __forceinline__ void atomicMinF(unsigned* addr, float v){
  if (v >= 0.f) atomicMin((int*)addr, (int)__float_as_uint(v));
  else          atomicMax(addr, __float_as_uint(v));
}

__global__ __launch_bounds__(256) void init_kernel(float* stats1, float* stats2a, float* stats2b,
                                                   unsigned* gmax, unsigned* gmin){
  int t = blockIdx.x*256 + threadIdx.x;
  if (t < 128) stats1[t] = 0.f;
  if (t < 256) stats2a[t] = 0.f;
  if (t < 512) stats2b[t] = 0.f;
  if (t < 4096){ gmax[t] = 0xFF800000u; gmin[t] = 0x7F800000u; }
}

// ---- knn chunk: 256 query threads vs CHUNK staged points; sorted u64 top-16 ----
template<int CHUNK>
__device__ __forceinline__ void knn_chunk_body(const float* __restrict__ pos_b, int qbase, int jbase,
                                               float4* sm, u64* __restrict__ out, int tid){
  for (int t = tid; t < CHUNK; t += 256){
    const float* p = pos_b + (size_t)(jbase + t)*3;
    float x = p[0], y = p[1], z = p[2];
    float n2 = frn_add(frn_add(frn_mul(x,x), frn_mul(y,y)), frn_mul(z,z));
    sm[t] = make_float4(x,y,z,n2);
  }
  __syncthreads();
  int i = qbase + tid;
  const float* qp = pos_b + (size_t)i*3;
  float xi = qp[0], yi = qp[1], zi = qp[2];
  float n2i = frn_add(frn_add(frn_mul(xi,xi), frn_mul(yi,yi)), frn_mul(zi,zi));
  u64 best[KNNK];
#pragma unroll
  for (int p = 0; p < KNNK; ++p) best[p] = ~0ull;
  for (int jj = 0; jj < CHUNK; ++jj){
    float4 v = sm[jj];
    float e = frn_add(frn_add(frn_mul(xi,v.x), frn_mul(yi,v.y)), frn_mul(zi,v.z));
    float d = frn_sub(frn_add(n2i, v.w), frn_mul(2.0f, e));
    u64 key = ((u64)f32_sortable(d) << 32) | (unsigned)(jbase + jj);
    if (key < best[KNNK-1]){
      u64 cur = key;
#pragma unroll
      for (int p = 0; p < KNNK; ++p){
        u64 mn = best[p] < cur ? best[p] : cur;
        u64 mx = best[p] < cur ? cur : best[p];
        best[p] = mn; cur = mx;
      }
    }
  }
#pragma unroll
  for (int p = 0; p < KNNK; ++p) out[p] = best[p];
}

// ---- K0: blocks 0..7 = DUAL-BATCH FPS (2 independent chains interleaved for ILP),
//          blocks 8..263 = knn1 chunks (r7-proven) ----
__global__ __launch_bounds__(256) void k0_fps_knn1(const float* __restrict__ pos,
    int* __restrict__ idxf, float* __restrict__ pos2, u64* __restrict__ pknn1){
  __shared__ __align__(16) char smem[57*1024];
  int tid = threadIdx.x;
  if (blockIdx.x < 8){
    int b0 = blockIdx.x*2, b1 = b0 + 1;
    float* pxA = (float*)smem;                 // 6 x 2048 floats = 48 KB
    float* pyA = pxA + 2048;
    float* pzA = pyA + 2048;
    float* pxB = pzA + 2048;
    float* pyB = pxB + 2048;
    float* pzB = pyB + 2048;
    int* selA = (int*)(smem + 48*1024);        // 1024 ints
    int* selB = selA + 1024;                   // 1024 ints (ends 56 KB)
    u64* wredA = (u64*)(smem + 56*1024);       // [2][4]
    u64* wredB = wredA + 8;
    const float* pbA = pos + (size_t)b0*NN*3;
    const float* pbB = pos + (size_t)b1*NN*3;
    float XA[8], YA[8], ZA[8], MDA[8];
    float XB[8], YB[8], ZB[8], MDB[8];
    unsigned LO[8];
#pragma unroll
    for (int q = 0; q < 8; ++q){
      int p = tid + 256*q;
      float xa = pbA[p*3+0], ya = pbA[p*3+1], za = pbA[p*3+2];
      float xb = pbB[p*3+0], yb = pbB[p*3+1], zb = pbB[p*3+2];
      XA[q]=xa; YA[q]=ya; ZA[q]=za;
      XB[q]=xb; YB[q]=yb; ZB[q]=zb;
      LO[q] = ~(unsigned)p;
      pxA[p]=xa; pyA[p]=ya; pzA[p]=za;
      pxB[p]=xb; pyB[p]=yb; pzB[p]=zb;
    }
    float qxA = pbA[0], qyA = pbA[1], qzA = pbA[2];
    float qxB = pbB[0], qyB = pbB[1], qzB = pbB[2];
#pragma unroll
    for (int q = 0; q < 8; ++q){
      float dxa = frn_sub(XA[q],qxA), dya = frn_sub(YA[q],qyA), dza = frn_sub(ZA[q],qzA);
      MDA[q] = frn_add(frn_add(frn_mul(dxa,dxa), frn_mul(dya,dya)), frn_mul(dza,dza));
      float dxb = frn_sub(XB[q],qxB), dyb = frn_sub(YB[q],qyB), dzb = frn_sub(ZB[q],qzB);
      MDB[q] = frn_add(frn_add(frn_mul(dxb,dxb), frn_mul(dyb,dyb)), frn_mul(dzb,dzb));
    }
    if (tid == 0){ selA[0] = 0; selB[0] = 0; }
    int wv = tid >> 6;
    __syncthreads();
#define TREE8(MD) ( umax64( umax64( \
      umax64(((u64)__float_as_uint(MD[0])<<32)|LO[0], ((u64)__float_as_uint(MD[1])<<32)|LO[1]), \
      umax64(((u64)__float_as_uint(MD[2])<<32)|LO[2], ((u64)__float_as_uint(MD[3])<<32)|LO[3])), umax64( \
      umax64(((u64)__float_as_uint(MD[4])<<32)|LO[4], ((u64)__float_as_uint(MD[5])<<32)|LO[5]), \
      umax64(((u64)__float_as_uint(MD[6])<<32)|LO[6], ((u64)__float_as_uint(MD[7])<<32)|LO[7])) ) )
#define RED_DPP(kk, CTRL) { \
      unsigned lo_ = (unsigned)kk, hi_ = (unsigned)(kk>>32); \
      unsigned plo = (unsigned)__builtin_amdgcn_update_dpp((int)lo_,(int)lo_,CTRL,0xF,0xF,false); \
      unsigned phi = (unsigned)__builtin_amdgcn_update_dpp((int)hi_,(int)hi_,CTRL,0xF,0xF,false); \
      u64 o = ((u64)phi<<32)|plo; kk = o > kk ? o : kk; }
    for (int s = 1; s < MM; ++s){
      u64 kkA = TREE8(MDA);
      u64 kkB = TREE8(MDB);
      RED_DPP(kkA, 0xB1)  RED_DPP(kkB, 0xB1)
      RED_DPP(kkA, 0x4E)  RED_DPP(kkB, 0x4E)
      RED_DPP(kkA, 0x124) RED_DPP(kkB, 0x124)
      RED_DPP(kkA, 0x128) RED_DPP(kkB, 0x128)
      RED_DPP(kkA, 0x142) RED_DPP(kkB, 0x142)
      RED_DPP(kkA, 0x143) RED_DPP(kkB, 0x143)
      int par = s & 1;
      if ((tid & 63) == 63){ wredA[par*4 + wv] = kkA; wredB[par*4 + wv] = kkB; }
      __syncthreads();
      const u64* wrA = wredA + par*4;
      const u64* wrB = wredB + par*4;
      u64 KA = umax64(umax64(wrA[0], wrA[1]), umax64(wrA[2], wrA[3]));
      u64 KB = umax64(umax64(wrB[0], wrB[1]), umax64(wrB[2], wrB[3]));
      unsigned wpA = ~(unsigned)KA;
      unsigned wpB = ~(unsigned)KB;
      float wxA = pxA[wpA], wyA = pyA[wpA], wzA = pzA[wpA];
      float wxB = pxB[wpB], wyB = pyB[wpB], wzB = pzB[wpB];
      if (tid == 0){ selA[s] = (int)wpA; selB[s] = (int)wpB; }
#pragma unroll
      for (int q = 0; q < 8; ++q){
        float dxa = frn_sub(XA[q],wxA), dya = frn_sub(YA[q],wyA), dza = frn_sub(ZA[q],wzA);
        float da = frn_add(frn_add(frn_mul(dxa,dxa), frn_mul(dya,dya)), frn_mul(dza,dza));
        MDA[q] = fminf(MDA[q], da);
        float dxb = frn_sub(XB[q],wxB), dyb = frn_sub(YB[q],wyB), dzb = frn_sub(ZB[q],wzB);
        float db = frn_add(frn_add(frn_mul(dxb,dxb), frn_mul(dyb,dyb)), frn_mul(dzb,dzb));
        MDB[q] = fminf(MDB[q], db);
      }
    }
#undef RED_DPP
#undef TREE8
    __syncthreads();
    for (int m = tid; m < MM; m += 256){
      int jA = selA[m];
      idxf[b0*MM + m] = jA;
      pos2[(size_t)(b0*MM+m)*3+0] = pxA[jA];
      pos2[(size_t)(b0*MM+m)*3+1] = pyA[jA];
      pos2[(size_t)(b0*MM+m)*3+2] = pzA[jA];
      int jB = selB[m];
      idxf[b1*MM + m] = jB;
      pos2[(size_t)(b1*MM+m)*3+0] = pxB[jB];
      pos2[(size_t)(b1*MM+m)*3+1] = pyB[jB];
      pos2[(size_t)(b1*MM+m)*3+2] = pzB[jB];
    }
  } else {
    int cid = blockIdx.x - 8;           // 0..255
    int b = cid >> 4;
    int rblk = (cid >> 1) & 7;
    int ch = cid & 1;
    float4* sm = (float4*)smem;         // 1024 * 16B
    const float* pos_b = pos + (size_t)b*NN*3;
    int i = rblk*256 + tid;
    u64* out = pknn1 + ((size_t)(b*NN + i)*2 + ch)*KNNK;
    knn_chunk_body<1024>(pos_b, rblk*256, ch*1024, sm, out, tid);
  }
}

// ---- K1: blocks 0..127 = merge1 (2-way), blocks 128..383 = knn2 chunks ----
__global__ __launch_bounds__(256) void k1_merge1_knn2(const u64* __restrict__ pknn1,
    int* __restrict__ idx1, const float* __restrict__ pos2, u64* __restrict__ pknn2){
  __shared__ __align__(16) float4 sm[256];
  int tid = threadIdx.x;
  if (blockIdx.x < 128){
    int row = blockIdx.x*256 + tid;     // 32768 rows
    const u64* A = pknn1 + (size_t)row*32;
    const u64* B = A + 16;
    int ia = 0, ib = 0;
    int* op = idx1 + (size_t)row*KNNK;
#pragma unroll
    for (int p = 0; p < KNNK; ++p){
      u64 ka = A[ia], kb = B[ib];
      if (ka < kb){ op[p] = (int)(unsigned)ka; ++ia; }
      else        { op[p] = (int)(unsigned)kb; ++ib; }
    }
  } else {
    int cid = blockIdx.x - 128;         // 0..255
    int b = cid >> 4;
    int rblk = (cid >> 2) & 3;
    int ch = cid & 3;
    const float* pos_b = pos2 + (size_t)b*MM*3;
    int i = rblk*256 + tid;
    u64* out = pknn2 + ((size_t)(b*MM + i)*4 + ch)*KNNK;
    knn_chunk_body<256>(pos_b, rblk*256, ch*256, sm, out, tid);
  }
}

// ---- K2: blocks 0..63 = merge2 (4-way), blocks 64..1087 = conv1 stats ----
__global__ __launch_bounds__(256) void k2_merge2_c1stats(const u64* __restrict__ pknn2,
    int* __restrict__ idx2, const float* __restrict__ pos, const int* __restrict__ idx1,
    const float* __restrict__ W1, const float* __restrict__ b1, float* __restrict__ stats1){
  __shared__ float red[4][64][2];
  int tid = threadIdx.x;
  if (blockIdx.x < 64){
    int row = blockIdx.x*256 + tid;     // 16384 rows
    const u64* L = pknn2 + (size_t)row*64;
    int o0=0, o1=0, o2=0, o3=0;
    int* op = idx2 + (size_t)row*KNNK;
#pragma unroll
    for (int p = 0; p < KNNK; ++p){
      u64 k0 = L[o0], k1 = L[16+o1], k2 = L[32+o2], k3 = L[48+o3];
      u64 m01 = k0 < k1 ? k0 : k1;
      u64 m23 = k2 < k3 ? k2 : k3;
      u64 m = m01 < m23 ? m01 : m23;
      op[p] = (int)(unsigned)m;
      o0 += (m == k0); o1 += (m == k1); o2 += (m == k2); o3 += (m == k3);
    }
    return;
  }
  int lane = tid & 63, wv = tid >> 6;
  int wave = (blockIdx.x - 64)*4 + wv;  // 0..4095, 8 rows each
  float w[6];
#pragma unroll
  for (int f = 0; f < 6; ++f) w[f] = W1[f*64 + lane];
  float bias = b1[lane];
  float ssum = 0.f, ssq = 0.f;
  for (int r = 0; r < 8; ++r){
    int row = wave*8 + r;
    int b = row >> 11, ii = row & 2047;
    const float* pi = pos + ((size_t)(b*NN + ii))*3;
    float xi = pi[0], yi = pi[1], zi = pi[2];
    const int* ip = idx1 + (size_t)row * KNNK;
#pragma unroll 4
    for (int k = 0; k < KNNK; ++k){
      int j = ip[k];
      const float* pj = pos + ((size_t)(b*NN + j))*3;
      float xj = pj[0], yj = pj[1], zj = pj[2];
      float y = bias;
      y = fmaf(xj, w[0], y); y = fmaf(yj, w[1], y); y = fmaf(zj, w[2], y);
      y = fmaf(xj - xi, w[3], y); y = fmaf(yj - yi, w[4], y); y = fmaf(zj - zi, w[5], y);
      ssum += y; ssq = fmaf(y, y, ssq);
    }
  }
  red[wv][lane][0] = ssum; red[wv][lane][1] = ssq;
  __syncthreads();
  if (tid < 64){
    float s = red[0][lane][0]+red[1][lane][0]+red[2][lane][0]+red[3][lane][0];
    float q = red[0][lane][1]+red[1][lane][1]+red[2][lane][1]+red[3][lane][1];
    atomicAdd(&stats1[lane], s);
    atomicAdd(&stats1[64+lane], q);
  }
}

__global__ __launch_bounds__(256) void conv1_apply_kernel(
    const float* __restrict__ pos, const int* __restrict__ idx1,
    const float* __restrict__ W1, const float* __restrict__ b1,
    const float* __restrict__ g1, const float* __restrict__ be1,
    const float* __restrict__ stats1, float* __restrict__ h){
  int lane = threadIdx.x & 63, wv = threadIdx.x >> 6;
  int wave = blockIdx.x*4 + wv;
  float w[6];
#pragma unroll
  for (int f = 0; f < 6; ++f) w[f] = W1[f*64 + lane];
  float bias = b1[lane];
  const float inv = 1.0f / (float)RC1;
  float mu = stats1[lane] * inv;
  float var = fmaxf(stats1[64+lane]*inv - mu*mu, 0.f);
  float sc = rsqrtf(var + 1e-5f) * g1[lane];
  float sh = be1[lane] - mu*sc;
  for (int r = 0; r < 8; ++r){
    int row = wave*8 + r;
    int b = row >> 11, ii = row & 2047;
    const float* pi = pos + ((size_t)(b*NN + ii))*3;
    float xi = pi[0], yi = pi[1], zi = pi[2];
    const int* ip = idx1 + (size_t)row * KNNK;
    float ymn = INFINITY, ymx = -INFINITY;
#pragma unroll 4
    for (int k = 0; k < KNNK; ++k){
      int j = ip[k];
      const float* pj = pos + ((size_t)(b*NN + j))*3;
      float xj = pj[0], yj = pj[1], zj = pj[2];
      float y = bias;
      y = fmaf(xj, w[0], y); y = fmaf(yj, w[1], y); y = fmaf(zj, w[2], y);
      y = fmaf(xj - xi, w[3], y); y = fmaf(yj - yi, w[4], y); y = fmaf(zj - zi, w[5], y);
      ymn = fminf(ymn, y); ymx = fmaxf(ymx, y);
    }
    h[((size_t)row << 6) + lane] = fmaxf(silu_f(fmaf(ymx, sc, sh)), silu_f(fmaf(ymn, sc, sh)));
  }
}

// ---- conv2a: 4 rows share weights; LDS weights stored as channel-pairs ->
//      one ds_read_b64 replaces two ds_read_b32 (same values, same FMA order) ----
__global__ __launch_bounds__(256) void conv2a_kernel(
    const float* __restrict__ h, const int* __restrict__ idxf,
    const float* __restrict__ pos2, const int* __restrict__ idx2,
    const float* __restrict__ W2a, const float* __restrict__ b2a,
    float* __restrict__ stats2a, __hip_bfloat16* __restrict__ y2a){
  __shared__ __align__(16) float Wl[67*128];   // Wl[f*128 + 2*c + i] = W2a[f*128 + c + 64*i]
  __shared__ float red[4][64][4];
  for (int t = threadIdx.x; t < 67*128; t += 256){
    int f = t >> 7, r = t & 127;
    Wl[t] = W2a[f*128 + (r >> 1) + (r & 1)*64];
  }
  __syncthreads();
  int lane = threadIdx.x & 63, wv = threadIdx.x >> 6;
  int wave = blockIdx.x*4 + wv;                 // 0..4095, 64 rows each
  float bias0 = b2a[lane], bias1 = b2a[64+lane];
  float ssum0=0, ssq0=0, ssum1=0, ssq1=0;
  for (int r4 = 0; r4 < 16; ++r4){
    int row0 = wave*64 + r4*4;
    int b = row0 >> 14;
    int m = (row0 >> 4) & 1023;
    int j0 = idx2[row0+0], j1 = idx2[row0+1], j2 = idx2[row0+2], j3 = idx2[row0+3];
    int q0 = idxf[b*MM + j0], q1 = idxf[b*MM + j1], q2 = idxf[b*MM + j2], q3 = idxf[b*MM + j3];
    const float4* h0 = (const float4*)(h + ((size_t)(b*NN + q0) << 6));
    const float4* h1 = (const float4*)(h + ((size_t)(b*NN + q1) << 6));
    const float4* h2 = (const float4*)(h + ((size_t)(b*NN + q2) << 6));
    const float4* h3 = (const float4*)(h + ((size_t)(b*NN + q3) << 6));
    float y00=bias0, y01=bias1, y10=bias0, y11=bias1;
    float y20=bias0, y21=bias1, y30=bias0, y31=bias1;
#define C2A_STEP(e, a0v, a1v, a2v, a3v) { \
      float2 wp2 = *(const float2*)&Wl[(e)*128 + lane*2]; \
      float w0_ = wp2.x, w1_ = wp2.y; \
      y00 = fmaf(a0v, w0_, y00); y01 = fmaf(a0v, w1_, y01); \
      y10 = fmaf(a1v, w0_, y10); y11 = fmaf(a1v, w1_, y11); \
      y20 = fmaf(a2v, w0_, y20); y21 = fmaf(a2v, w1_, y21); \
      y30 = fmaf(a3v, w0_, y30); y31 = fmaf(a3v, w1_, y31); }
#pragma unroll
    for (int f4 = 0; f4 < 16; ++f4){
      float4 v0 = h0[f4], v1 = h1[f4], v2 = h2[f4], v3 = h3[f4];
      C2A_STEP(f4*4+0, v0.x, v1.x, v2.x, v3.x)
      C2A_STEP(f4*4+1, v0.y, v1.y, v2.y, v3.y)
      C2A_STEP(f4*4+2, v0.z, v1.z, v2.z, v3.z)
      C2A_STEP(f4*4+3, v0.w, v1.w, v2.w, v3.w)
    }
    const float* pm = pos2 + ((size_t)(b*MM + m))*3;
    float pmx = pm[0], pmy = pm[1], pmz = pm[2];
    const float* pj0 = pos2 + ((size_t)(b*MM + j0))*3;
    const float* pj1 = pos2 + ((size_t)(b*MM + j1))*3;
    const float* pj2 = pos2 + ((size_t)(b*MM + j2))*3;
    const float* pj3 = pos2 + ((size_t)(b*MM + j3))*3;
    C2A_STEP(64, pj0[0]-pmx, pj1[0]-pmx, pj2[0]-pmx, pj3[0]-pmx)
    C2A_STEP(65, pj0[1]-pmy, pj1[1]-pmy, pj2[1]-pmy, pj3[1]-pmy)
    C2A_STEP(66, pj0[2]-pmz, pj1[2]-pmz, pj2[2]-pmz, pj3[2]-pmz)
#undef C2A_STEP
    ssum0 += y00+y10+y20+y30;
    ssum1 += y01+y11+y21+y31;
    ssq0 = fmaf(y00,y00,fmaf(y10,y10,fmaf(y20,y20,fmaf(y30,y30,ssq0))));
    ssq1 = fmaf(y01,y01,fmaf(y11,y11,fmaf(y21,y21,fmaf(y31,y31,ssq1))));
    y2a[(size_t)(row0+0)*128 + lane]      = __float2bfloat16(y00);
    y2a[(size_t)(row0+0)*128 + 64 + lane] = __float2bfloat16(y01);
    y2a[(size_t)(row0+1)*128 + lane]      = __float2bfloat16(y10);
    y2a[(size_t)(row0+1)*128 + 64 + lane] = __float2bfloat16(y11);
    y2a[(size_t)(row0+2)*128 + lane]      = __float2bfloat16(y20);
    y2a[(size_t)(row0+2)*128 + 64 + lane] = __float2bfloat16(y21);
    y2a[(size_t)(row0+3)*128 + lane]      = __float2bfloat16(y30);
    y2a[(size_t)(row0+3)*128 + 64 + lane] = __float2bfloat16(y31);
  }
  red[wv][lane][0]=ssum0; red[wv][lane][1]=ssq0; red[wv][lane][2]=ssum1; red[wv][lane][3]=ssq1;
  __syncthreads();
  if (threadIdx.x < 64){
    float s0=0,q0=0,s1=0,q1=0;
#pragma unroll
    for (int v2=0; v2<4; ++v2){ s0+=red[v2][lane][0]; q0+=red[v2][lane][1]; s1+=red[v2][lane][2]; q1+=red[v2][lane][3]; }
    atomicAdd(&stats2a[lane], s0);      atomicAdd(&stats2a[128+lane], q0);
    atomicAdd(&stats2a[64+lane], s1);   atomicAdd(&stats2a[192+lane], q1);
  }
}

// ---- conv2b: MFMA 16x16x32 bf16 (r7-proven) ----
__global__ __launch_bounds__(256) void conv2b_kernel(
    const __hip_bfloat16* __restrict__ y2a, const float* __restrict__ stats2a,
    const float* __restrict__ g2a, const float* __restrict__ be2a,
    const float* __restrict__ W2b, const float* __restrict__ b2b,
    float* __restrict__ stats2b, unsigned* __restrict__ gmax, unsigned* __restrict__ gmin){
  __shared__ __align__(16) char Albs[64*256];
  __shared__ __align__(16) char Btbs[64*256];
  __shared__ float sc2a[128], sh2a[128];
  int tid = threadIdx.x;
  int lane = tid & 63, wvi = tid >> 6;
  int ct = blockIdx.x & 3;
  int rb = blockIdx.x >> 2;
  int c0 = ct * 64;
  int batch = rb >> 5;
  if (tid < 128){
    const float inv = 1.0f / (float)RC2;
    float mu = stats2a[tid] * inv;
    float var = fmaxf(stats2a[128+tid]*inv - mu*mu, 0.f);
    float s = rsqrtf(var + 1e-5f) * g2a[tid];
    sc2a[tid] = s; sh2a[tid] = be2a[tid] - mu*s;
  }
  {
    int cc = tid & 63, u0 = tid >> 6;
#pragma unroll
    for (int i = 0; i < 4; ++i){
      int u = u0 + i*4;
      unsigned short hb[8];
#pragma unroll
      for (int e = 0; e < 8; ++e) hb[e] = f2bf(W2b[(size_t)(u*8+e)*256 + c0 + cc]);
      *(short8*)(Btbs + cc*256 + u*16) = *(short8*)hb;
    }
  }
  __syncthreads();
  short8 bfrag[4];
#pragma unroll
  for (int kb4 = 0; kb4 < 4; ++kb4){
    int col_local = wvi*16 + (lane & 15);
    bfrag[kb4] = *(short8*)(Btbs + col_local*256 + kb4*64 + (lane>>4)*16);
  }
  float bb = b2b[c0 + wvi*16 + (lane & 15)];
  float vmn = INFINITY, vmx = -INFINITY, ssum = 0.f, ssq = 0.f;
  const unsigned short* y2u = (const unsigned short*)y2a;
  int sr = tid & 63, su = tid >> 6;
  for (int tile = 0; tile < 8; ++tile){
    int row0 = rb*512 + tile*64;
    if (tile > 0) __syncthreads();
#pragma unroll
    for (int i = 0; i < 4; ++i){
      int u = su + i*4;
      short8 v = *(const short8*)(y2u + (size_t)(row0 + sr)*128 + u*8);
      unsigned short ha[8];
#pragma unroll
      for (int e = 0; e < 8; ++e){
        int k = u*8 + e;
        float f = bf2f((unsigned short)v[e]);
        ha[e] = f2bf(silu_f(fmaf(f, sc2a[k], sh2a[k])));
      }
      *(short8*)(Albs + sr*256 + ((u*16) ^ ((sr & 7) << 4))) = *(short8*)ha;
    }
    __syncthreads();
#pragma unroll
    for (int sl = 0; sl < 4; ++sl){
      f32x4 acc = {0.f, 0.f, 0.f, 0.f};
#pragma unroll
      for (int kb4 = 0; kb4 < 4; ++kb4){
        int r = sl*16 + (lane & 15);
        short8 afrag = *(short8*)(Albs + r*256 + ((kb4*64 + (lane>>4)*16) ^ ((r & 7) << 4)));
        acc = __builtin_amdgcn_mfma_f32_16x16x32_bf16(afrag, bfrag[kb4], acc, 0, 0, 0);
      }
#pragma unroll
      for (int j = 0; j < 4; ++j){
        float y = acc[j] + bb;
        vmn = fminf(vmn, y); vmx = fmaxf(vmx, y);
        ssum += y; ssq = fmaf(y, y, ssq);
      }
    }
  }
#pragma unroll
  for (int off = 16; off <= 32; off += 16){
    vmn  = fminf(vmn,  __shfl_xor(vmn,  off));
    vmx  = fmaxf(vmx,  __shfl_xor(vmx,  off));
    ssum = ssum + __shfl_xor(ssum, off);
    ssq  = ssq  + __shfl_xor(ssq,  off);
  }
  if ((lane >> 4) == 0){
    int c = c0 + wvi*16 + lane;
    atomicAdd(&stats2b[c], ssum);
    atomicAdd(&stats2b[256+c], ssq);
    atomicMaxF(&gmax[batch*256 + c], vmx);
    atomicMinF(&gmin[batch*256 + c], vmn);
  }
}

__global__ __launch_bounds__(256) void final_kernel(
    const float* __restrict__ stats2b, const unsigned* __restrict__ gmax,
    const unsigned* __restrict__ gmin, const float* __restrict__ g2b,
    const float* __restrict__ be2b, float* __restrict__ out){
  int t = blockIdx.x*256 + threadIdx.x;
  if (t >= NB*256) return;
  int c = t & 255;
  const float inv = 1.0f / (float)RC2;
  float mu = stats2b[c]*inv;
  float var = fmaxf(stats2b[256+c]*inv - mu*mu, 0.f);
  float sc = rsqrtf(var + 1e-5f)*g2b[c];
  float sh = be2b[c] - mu*sc;
  float mx = __uint_as_float(gmax[t]);
  float mn = __uint_as_float(gmin[t]);
  out[t] = fmaxf(silu_f(fmaf(mx, sc, sh)), silu_f(fmaf(mn, sc, sh)));
}

extern "C" void kernel_launch(void* const* d_in, const int* in_sizes, int n_in,
                              void* d_out, int out_size, void* d_ws, size_t ws_size,
                              hipStream_t stream){
  (void)in_sizes; (void)n_in; (void)out_size; (void)ws_size;
  const float* pos  = (const float*)d_in[0];
  const float* W1   = (const float*)d_in[1];
  const float* b1   = (const float*)d_in[2];
  const float* g1   = (const float*)d_in[3];
  const float* be1  = (const float*)d_in[4];
  const float* W2a  = (const float*)d_in[5];
  const float* b2a  = (const float*)d_in[6];
  const float* g2a  = (const float*)d_in[7];
  const float* be2a = (const float*)d_in[8];
  const float* W2b  = (const float*)d_in[9];
  const float* b2b  = (const float*)d_in[10];
  const float* g2b  = (const float*)d_in[11];
  const float* be2b = (const float*)d_in[12];

  char* w = (char*)d_ws;
  size_t off = 0;
  auto carve = [&](size_t bytes)->void*{ void* p = w + off; off += (bytes + 255) & ~(size_t)255; return p; };
  int*      idx1    = (int*)carve((size_t)NB*NN*KNNK*4);      // 2 MB
  float*    h       = (float*)carve((size_t)NB*NN*64*4);      // 8 MB
  int*      idxf    = (int*)carve((size_t)NB*MM*4);
  float*    pos2    = (float*)carve((size_t)NB*MM*3*4);
  int*      idx2    = (int*)carve((size_t)NB*MM*KNNK*4);      // 1 MB
  float*    stats1  = (float*)carve(128*4);
  float*    stats2a = (float*)carve(256*4);
  float*    stats2b = (float*)carve(512*4);
  unsigned* gmax    = (unsigned*)carve(4096*4);
  unsigned* gmin    = (unsigned*)carve(4096*4);
  __hip_bfloat16* y2a = (__hip_bfloat16*)carve((size_t)RC2*128*2);  // 64 MB
  // pknn buffers live inside the y2a region (dead before conv2a writes y2a)
  u64* pknn1 = (u64*)y2a;                          // 8 MB  (dead after K1)
  u64* pknn2 = (u64*)((char*)y2a + (32u<<20));     // 8 MB  (dead after K2)

  init_kernel<<<dim3(16), dim3(256), 0, stream>>>(stats1, stats2a, stats2b, gmax, gmin);
  k0_fps_knn1<<<dim3(264), dim3(256), 0, stream>>>(pos, idxf, pos2, pknn1);
  k1_merge1_knn2<<<dim3(384), dim3(256), 0, stream>>>(pknn1, idx1, pos2, pknn2);
  k2_merge2_c1stats<<<dim3(1088), dim3(256), 0, stream>>>(pknn2, idx2, pos, idx1, W1, b1, stats1);
  conv1_apply_kernel<<<dim3(1024), dim3(256), 0, stream>>>(pos, idx1, W1, b1, g1, be1, stats1, h);
  conv2a_kernel<<<dim3(1024), dim3(256), 0, stream>>>(h, idxf, pos2, idx2, W2a, b2a, stats2a, y2a);
  conv2b_kernel<<<dim3(2048), dim3(256), 0, stream>>>(y2a, stats2a, g2a, be2a, W2b, b2b, stats2b, gmax, gmin);
  final_kernel<<<dim3(16), dim3(256), 0, stream>>>(stats2b, gmax, gmin, g2b, be2b, (float*)d_out);
}

// Round 11
// 943.332 us; speedup vs baseline: 1.8468x; 1.3301x over previous
//
#include <hip/hip_runtime.h>
#include <hip/hip_bf16.h>

#define NB 16
#define NN 2048
#define KNNK 16
#define MM 1024
#define RC1 (NB*NN*KNNK)   // 524288 conv1 BN rows
#define RC2 (NB*MM*KNNK)   // 262144 conv2 BN rows

typedef unsigned long long u64;
typedef __attribute__((ext_vector_type(8))) short short8;
typedef __attribute__((ext_vector_type(4))) float f32x4;

__device__ __forceinline__ float frn_mul(float a, float b){ return __fmul_rn(a,b); }
__device__ __forceinline__ float frn_add(float a, float b){ return __fadd_rn(a,b); }
__device__ __forceinline__ float frn_sub(float a, float b){ return __fsub_rn(a,b); }
__device__ __forceinline__ float silu_f(float x){ return x / (1.0f + __expf(-x)); }
__device__ __forceinline__ u64 umax64(u64 a, u64 b){ return a > b ? a : b; }

__device__ __forceinline__ unsigned f32_sortable(float f){
  unsigned u = __float_as_uint(f);
  return u ^ ((unsigned)((int)u >> 31) | 0x80000000u);
}
__device__ __forceinline__ unsigned short f2bf(float f){
  unsigned u = __float_as_uint(f);
  return (unsigned short)((u + 0x7FFFu + ((u >> 16) & 1u)) >> 16);
}
__device__ __forceinline__ float bf2f(unsigned short h){
  return __uint_as_float(((unsigned)h) << 16);
}

__device__ __forceinline__ void atomicMaxF(unsigned* addr, float v){
  if (v >= 0.f) atomicMax((int*)addr, (int)__float_as_uint(v));
  else          atomicMin(addr, __float_as_uint(v));
}
__device__ __forceinline__ void atomicMinF(unsigned* addr, float v){
  if (v >= 0.f) atomicMin((int*)addr, (int)__float_as_uint(v));
  else          atomicMax(addr, __float_as_uint(v));
}

__global__ __launch_bounds__(256) void init_kernel(float* stats1, float* stats2a, float* stats2b,
                                                   unsigned* gmax, unsigned* gmin){
  int t = blockIdx.x*256 + threadIdx.x;
  if (t < 128) stats1[t] = 0.f;
  if (t < 256) stats2a[t] = 0.f;
  if (t < 512) stats2b[t] = 0.f;
  if (t < 4096){ gmax[t] = 0xFF800000u; gmin[t] = 0x7F800000u; }
}

// insertion scan over [jbase, jbase+CNT) LDS points; best[] sorted ascending
template<int CNT>
__device__ __forceinline__ void knn_scan(const float4* pts, int jbase,
                                         float xi, float yi, float zi, float n2i, u64* best){
#pragma unroll
  for (int p = 0; p < KNNK; ++p) best[p] = ~0ull;
  for (int jj = 0; jj < CNT; ++jj){
    float4 v = pts[jbase + jj];
    float e = frn_add(frn_add(frn_mul(xi,v.x), frn_mul(yi,v.y)), frn_mul(zi,v.z));
    float d = frn_sub(frn_add(n2i, v.w), frn_mul(2.0f, e));
    u64 key = ((u64)f32_sortable(d) << 32) | (unsigned)(jbase + jj);
    if (key < best[KNNK-1]){
      u64 cur = key;
#pragma unroll
      for (int p = 0; p < KNNK; ++p){
        u64 mn = best[p] < cur ? best[p] : cur;
        u64 mx = best[p] < cur ? cur : best[p];
        best[p] = mn; cur = mx;
      }
    }
  }
}

// ---- K0: blocks 0..15 = FPS (r7 verbatim); blocks 16..271 = knn1 chunk scan +
//      in-block merge + conv1 stats (chunk math identical to r7 -> same indices) ----
__global__ __launch_bounds__(256) void k0_fps_knn1(const float* __restrict__ pos,
    int* __restrict__ idxf, float* __restrict__ pos2, int* __restrict__ idx1,
    const float* __restrict__ W1, const float* __restrict__ b1, float* __restrict__ stats1){
  __shared__ __align__(16) char smem[74*1024];
  int tid = threadIdx.x;
  if (blockIdx.x < 16){
    int b = blockIdx.x;
    float4* pts4 = (float4*)smem;                    // 2048 * 16B = 32 KB
    int* sel = (int*)(smem + 32*1024);               // 1024 ints
    u64* wred = (u64*)(smem + 36*1024);              // [2][4]
    const float* pb = pos + (size_t)b*NN*3;
    float X[8], Y[8], Z[8], MD[8];
    unsigned LO[8];
#pragma unroll
    for (int q = 0; q < 8; ++q){
      int p = tid + 256*q;
      float x = pb[p*3+0], y = pb[p*3+1], z = pb[p*3+2];
      X[q] = x; Y[q] = y; Z[q] = z;
      LO[q] = ~(unsigned)p;
      pts4[p] = make_float4(x, y, z, 0.f);
    }
    float qx = pb[0], qy = pb[1], qz = pb[2];
#pragma unroll
    for (int q = 0; q < 8; ++q){
      float dx = frn_sub(X[q],qx), dy = frn_sub(Y[q],qy), dz = frn_sub(Z[q],qz);
      MD[q] = frn_add(frn_add(frn_mul(dx,dx), frn_mul(dy,dy)), frn_mul(dz,dz));
    }
    if (tid == 0) sel[0] = 0;
    int wv = tid >> 6;
    __syncthreads();
    for (int s = 1; s < MM; ++s){
      u64 t0 = umax64(((u64)__float_as_uint(MD[0])<<32)|LO[0], ((u64)__float_as_uint(MD[1])<<32)|LO[1]);
      u64 t1 = umax64(((u64)__float_as_uint(MD[2])<<32)|LO[2], ((u64)__float_as_uint(MD[3])<<32)|LO[3]);
      u64 t2 = umax64(((u64)__float_as_uint(MD[4])<<32)|LO[4], ((u64)__float_as_uint(MD[5])<<32)|LO[5]);
      u64 t3 = umax64(((u64)__float_as_uint(MD[6])<<32)|LO[6], ((u64)__float_as_uint(MD[7])<<32)|LO[7]);
      u64 kk = umax64(umax64(t0, t1), umax64(t2, t3));
#define RED_DPP(CTRL) { \
      unsigned lo_ = (unsigned)kk, hi_ = (unsigned)(kk>>32); \
      unsigned plo = (unsigned)__builtin_amdgcn_update_dpp((int)lo_,(int)lo_,CTRL,0xF,0xF,false); \
      unsigned phi = (unsigned)__builtin_amdgcn_update_dpp((int)hi_,(int)hi_,CTRL,0xF,0xF,false); \
      u64 o = ((u64)phi<<32)|plo; kk = o > kk ? o : kk; }
      RED_DPP(0xB1)
      RED_DPP(0x4E)
      RED_DPP(0x124)
      RED_DPP(0x128)
      RED_DPP(0x142)
      RED_DPP(0x143)
#undef RED_DPP
      int par = s & 1;
      if ((tid & 63) == 63) wred[par*4 + wv] = kk;
      __syncthreads();
      const u64* wr = wred + par*4;
      u64 K = umax64(umax64(wr[0], wr[1]), umax64(wr[2], wr[3]));
      unsigned wp = ~(unsigned)K;
      if (tid == 0) sel[s] = (int)wp;
      float4 wc = pts4[wp];
#pragma unroll
      for (int q = 0; q < 8; ++q){
        float dx = frn_sub(X[q],wc.x), dy = frn_sub(Y[q],wc.y), dz = frn_sub(Z[q],wc.z);
        float d = frn_add(frn_add(frn_mul(dx,dx), frn_mul(dy,dy)), frn_mul(dz,dz));
        MD[q] = fminf(MD[q], d);
      }
    }
    __syncthreads();
    for (int m = tid; m < MM; m += 256){
      int j = sel[m];
      idxf[b*MM + m] = j;
      float4 c = pts4[j];
      pos2[(size_t)(b*MM+m)*3+0] = c.x;
      pos2[(size_t)(b*MM+m)*3+1] = c.y;
      pos2[(size_t)(b*MM+m)*3+2] = c.z;
    }
  } else {
    int cid = blockIdx.x - 16;           // 0..255
    int b = cid >> 4;
    int rb16 = cid & 15;                 // 128-row group
    float4* pts4 = (float4*)smem;        // 32 KB (x,y,z,n2)
    u64* cres = (u64*)(smem + 32*1024);  // 256 threads * 16 keys = 32 KB
    int* idxl = (int*)(smem + 64*1024);  // 128 rows * 16 = 8 KB
    float* red = (float*)(smem + 72*1024); // 4*64*2 = 2 KB
    const float* pb = pos + (size_t)b*NN*3;
    for (int i = tid; i < NN; i += 256){
      float x = pb[i*3+0], y = pb[i*3+1], z = pb[i*3+2];
      float n2 = frn_add(frn_add(frn_mul(x,x), frn_mul(y,y)), frn_mul(z,z));
      pts4[i] = make_float4(x, y, z, n2);
    }
    __syncthreads();
    int lrow = tid & 127;
    int ch = tid >> 7;                   // chunk 0 or 1
    int i = rb16*128 + lrow;
    float4 qv = pts4[i];
    u64 best[KNNK];
    knn_scan<1024>(pts4, ch*1024, qv.x, qv.y, qv.z, qv.w, best);
#pragma unroll
    for (int p = 0; p < KNNK; ++p) cres[tid*KNNK + p] = best[p];
    __syncthreads();
    if (tid < 128){
      const u64* A = cres + tid*KNNK;
      const u64* B = cres + (tid + 128)*KNNK;
      int ia = 0, ib = 0;
      int* op = idx1 + ((size_t)(b*NN + rb16*128 + tid))*KNNK;
#pragma unroll
      for (int p = 0; p < KNNK; ++p){
        u64 ka = A[ia], kb = B[ib];
        int v;
        if (ka < kb){ v = (int)(unsigned)ka; ++ia; }
        else        { v = (int)(unsigned)kb; ++ib; }
        op[p] = v;
        idxl[tid*KNNK + p] = v;
      }
    }
    __syncthreads();
    // conv1 stats for these 128 rows, all inputs in LDS
    int lane = tid & 63, wv = tid >> 6;
    float w[6];
#pragma unroll
    for (int f = 0; f < 6; ++f) w[f] = W1[f*64 + lane];
    float bias = b1[lane];
    float ssum = 0.f, ssq = 0.f;
    for (int r = 0; r < 32; ++r){
      int lr = wv*32 + r;
      float4 pi = pts4[rb16*128 + lr];
      const int* ip = idxl + lr*KNNK;
#pragma unroll 4
      for (int k = 0; k < KNNK; ++k){
        int j = ip[k];
        float4 pj = pts4[j];
        float y = bias;
        y = fmaf(pj.x, w[0], y); y = fmaf(pj.y, w[1], y); y = fmaf(pj.z, w[2], y);
        y = fmaf(pj.x - pi.x, w[3], y); y = fmaf(pj.y - pi.y, w[4], y); y = fmaf(pj.z - pi.z, w[5], y);
        ssum += y; ssq = fmaf(y, y, ssq);
      }
    }
    red[(wv*64+lane)*2+0] = ssum; red[(wv*64+lane)*2+1] = ssq;
    __syncthreads();
    if (tid < 64){
      float s = red[(0*64+lane)*2]+red[(1*64+lane)*2]+red[(2*64+lane)*2]+red[(3*64+lane)*2];
      float q = red[(0*64+lane)*2+1]+red[(1*64+lane)*2+1]+red[(2*64+lane)*2+1]+red[(3*64+lane)*2+1];
      atomicAdd(&stats1[lane], s);
      atomicAdd(&stats1[64+lane], q);
    }
  }
}

// ---- K1: blocks 0..255 = knn2 (4 chunks + in-block merge), 256..1279 = conv1 apply ----
__global__ __launch_bounds__(256) void k1_knn2_c1apply(
    const float* __restrict__ pos2, int* __restrict__ idx2,
    const float* __restrict__ pos, const int* __restrict__ idx1,
    const float* __restrict__ W1, const float* __restrict__ b1,
    const float* __restrict__ g1, const float* __restrict__ be1,
    const float* __restrict__ stats1, float* __restrict__ h){
  __shared__ __align__(16) char smem[48*1024];
  int tid = threadIdx.x;
  if (blockIdx.x < 256){
    int b = blockIdx.x >> 4;
    int rb = blockIdx.x & 15;            // 64-row group
    float4* sm = (float4*)smem;          // 1024 * 16B = 16 KB
    u64* cres = (u64*)(smem + 16*1024);  // 256 * 16 * 8 = 32 KB
    const float* pb = pos2 + (size_t)b*MM*3;
    for (int t = tid; t < MM; t += 256){
      float x = pb[t*3+0], y = pb[t*3+1], z = pb[t*3+2];
      float n2 = frn_add(frn_add(frn_mul(x,x), frn_mul(y,y)), frn_mul(z,z));
      sm[t] = make_float4(x, y, z, n2);
    }
    __syncthreads();
    int trow = tid & 63, ch = tid >> 6;  // 4 chunks of 256
    int i = rb*64 + trow;
    float4 qv = sm[i];
    u64 best[KNNK];
    knn_scan<256>(sm, ch*256, qv.x, qv.y, qv.z, qv.w, best);
#pragma unroll
    for (int p = 0; p < KNNK; ++p) cres[tid*KNNK + p] = best[p];
    __syncthreads();
    if (tid < 64){
      const u64* L0 = cres + tid*KNNK;
      const u64* L1 = cres + (64 + tid)*KNNK;
      const u64* L2 = cres + (128 + tid)*KNNK;
      const u64* L3 = cres + (192 + tid)*KNNK;
      int o0=0, o1=0, o2=0, o3=0;
      int* op = idx2 + ((size_t)(b*MM + rb*64 + tid))*KNNK;
#pragma unroll
      for (int p = 0; p < KNNK; ++p){
        u64 k0 = L0[o0], k1 = L1[o1], k2 = L2[o2], k3 = L3[o3];
        u64 m01 = k0 < k1 ? k0 : k1;
        u64 m23 = k2 < k3 ? k2 : k3;
        u64 m = m01 < m23 ? m01 : m23;
        op[p] = (int)(unsigned)m;
        o0 += (m == k0); o1 += (m == k1); o2 += (m == k2); o3 += (m == k3);
      }
    }
  } else {
    int lane = tid & 63, wv = tid >> 6;
    int wave = (blockIdx.x - 256)*4 + wv;
    float w[6];
#pragma unroll
    for (int f = 0; f < 6; ++f) w[f] = W1[f*64 + lane];
    float bias = b1[lane];
    const float inv = 1.0f / (float)RC1;
    float mu = stats1[lane] * inv;
    float var = fmaxf(stats1[64+lane]*inv - mu*mu, 0.f);
    float sc = rsqrtf(var + 1e-5f) * g1[lane];
    float sh = be1[lane] - mu*sc;
    for (int r = 0; r < 8; ++r){
      int row = wave*8 + r;
      int b = row >> 11, ii = row & 2047;
      const float* pi = pos + ((size_t)(b*NN + ii))*3;
      float xi = pi[0], yi = pi[1], zi = pi[2];
      const int* ip = idx1 + (size_t)row * KNNK;
      float ymn = INFINITY, ymx = -INFINITY;
#pragma unroll 4
      for (int k = 0; k < KNNK; ++k){
        int j = ip[k];
        const float* pj = pos + ((size_t)(b*NN + j))*3;
        float xj = pj[0], yj = pj[1], zj = pj[2];
        float y = bias;
        y = fmaf(xj, w[0], y); y = fmaf(yj, w[1], y); y = fmaf(zj, w[2], y);
        y = fmaf(xj - xi, w[3], y); y = fmaf(yj - yi, w[4], y); y = fmaf(zj - zi, w[5], y);
        ymn = fminf(ymn, y); ymx = fmaxf(ymx, y);
      }
      h[((size_t)row << 6) + lane] = fmaxf(silu_f(fmaf(ymx, sc, sh)), silu_f(fmaf(ymn, sc, sh)));
    }
  }
}

// ---- conv2a: r7 verbatim (4 rows share each LDS weight read) ----
__global__ __launch_bounds__(256) void conv2a_kernel(
    const float* __restrict__ h, const int* __restrict__ idxf,
    const float* __restrict__ pos2, const int* __restrict__ idx2,
    const float* __restrict__ W2a, const float* __restrict__ b2a,
    float* __restrict__ stats2a, __hip_bfloat16* __restrict__ y2a){
  __shared__ float Wl[67*128];
  __shared__ float red[4][64][4];
  for (int t = threadIdx.x; t < 67*128; t += 256) Wl[t] = W2a[t];
  __syncthreads();
  int lane = threadIdx.x & 63, wv = threadIdx.x >> 6;
  int wave = blockIdx.x*4 + wv;                 // 0..4095, 64 rows each
  float bias0 = b2a[lane], bias1 = b2a[64+lane];
  float ssum0=0, ssq0=0, ssum1=0, ssq1=0;
  for (int r4 = 0; r4 < 16; ++r4){
    int row0 = wave*64 + r4*4;
    int b = row0 >> 14;
    int m = (row0 >> 4) & 1023;
    int j0 = idx2[row0+0], j1 = idx2[row0+1], j2 = idx2[row0+2], j3 = idx2[row0+3];
    int q0 = idxf[b*MM + j0], q1 = idxf[b*MM + j1], q2 = idxf[b*MM + j2], q3 = idxf[b*MM + j3];
    const float4* h0 = (const float4*)(h + ((size_t)(b*NN + q0) << 6));
    const float4* h1 = (const float4*)(h + ((size_t)(b*NN + q1) << 6));
    const float4* h2 = (const float4*)(h + ((size_t)(b*NN + q2) << 6));
    const float4* h3 = (const float4*)(h + ((size_t)(b*NN + q3) << 6));
    float y00=bias0, y01=bias1, y10=bias0, y11=bias1;
    float y20=bias0, y21=bias1, y30=bias0, y31=bias1;
#define C2A_STEP(e, a0v, a1v, a2v, a3v) { \
      float w0_ = Wl[(e)*128 + lane], w1_ = Wl[(e)*128 + 64 + lane]; \
      y00 = fmaf(a0v, w0_, y00); y01 = fmaf(a0v, w1_, y01); \
      y10 = fmaf(a1v, w0_, y10); y11 = fmaf(a1v, w1_, y11); \
      y20 = fmaf(a2v, w0_, y20); y21 = fmaf(a2v, w1_, y21); \
      y30 = fmaf(a3v, w0_, y30); y31 = fmaf(a3v, w1_, y31); }
#pragma unroll
    for (int f4 = 0; f4 < 16; ++f4){
      float4 v0 = h0[f4], v1 = h1[f4], v2 = h2[f4], v3 = h3[f4];
      C2A_STEP(f4*4+0, v0.x, v1.x, v2.x, v3.x)
      C2A_STEP(f4*4+1, v0.y, v1.y, v2.y, v3.y)
      C2A_STEP(f4*4+2, v0.z, v1.z, v2.z, v3.z)
      C2A_STEP(f4*4+3, v0.w, v1.w, v2.w, v3.w)
    }
    const float* pm = pos2 + ((size_t)(b*MM + m))*3;
    float pmx = pm[0], pmy = pm[1], pmz = pm[2];
    const float* pj0 = pos2 + ((size_t)(b*MM + j0))*3;
    const float* pj1 = pos2 + ((size_t)(b*MM + j1))*3;
    const float* pj2 = pos2 + ((size_t)(b*MM + j2))*3;
    const float* pj3 = pos2 + ((size_t)(b*MM + j3))*3;
    C2A_STEP(64, pj0[0]-pmx, pj1[0]-pmx, pj2[0]-pmx, pj3[0]-pmx)
    C2A_STEP(65, pj0[1]-pmy, pj1[1]-pmy, pj2[1]-pmy, pj3[1]-pmy)
    C2A_STEP(66, pj0[2]-pmz, pj1[2]-pmz, pj2[2]-pmz, pj3[2]-pmz)
#undef C2A_STEP
    ssum0 += y00+y10+y20+y30;
    ssum1 += y01+y11+y21+y31;
    ssq0 = fmaf(y00,y00,fmaf(y10,y10,fmaf(y20,y20,fmaf(y30,y30,ssq0))));
    ssq1 = fmaf(y01,y01,fmaf(y11,y11,fmaf(y21,y21,fmaf(y31,y31,ssq1))));
    y2a[(size_t)(row0+0)*128 + lane]      = __float2bfloat16(y00);
    y2a[(size_t)(row0+0)*128 + 64 + lane] = __float2bfloat16(y01);
    y2a[(size_t)(row0+1)*128 + lane]      = __float2bfloat16(y10);
    y2a[(size_t)(row0+1)*128 + 64 + lane] = __float2bfloat16(y11);
    y2a[(size_t)(row0+2)*128 + lane]      = __float2bfloat16(y20);
    y2a[(size_t)(row0+2)*128 + 64 + lane] = __float2bfloat16(y21);
    y2a[(size_t)(row0+3)*128 + lane]      = __float2bfloat16(y30);
    y2a[(size_t)(row0+3)*128 + 64 + lane] = __float2bfloat16(y31);
  }
  red[wv][lane][0]=ssum0; red[wv][lane][1]=ssq0; red[wv][lane][2]=ssum1; red[wv][lane][3]=ssq1;
  __syncthreads();
  if (threadIdx.x < 64){
    float s0=0,q0=0,s1=0,q1=0;
#pragma unroll
    for (int v2=0; v2<4; ++v2){ s0+=red[v2][lane][0]; q0+=red[v2][lane][1]; s1+=red[v2][lane][2]; q1+=red[v2][lane][3]; }
    atomicAdd(&stats2a[lane], s0);      atomicAdd(&stats2a[128+lane], q0);
    atomicAdd(&stats2a[64+lane], s1);   atomicAdd(&stats2a[192+lane], q1);
  }
}

// ---- conv2b: MFMA 16x16x32 bf16 (r7 verbatim) ----
__global__ __launch_bounds__(256) void conv2b_kernel(
    const __hip_bfloat16* __restrict__ y2a, const float* __restrict__ stats2a,
    const float* __restrict__ g2a, const float* __restrict__ be2a,
    const float* __restrict__ W2b, const float* __restrict__ b2b,
    float* __restrict__ stats2b, unsigned* __restrict__ gmax, unsigned* __restrict__ gmin){
  __shared__ __align__(16) char Albs[64*256];
  __shared__ __align__(16) char Btbs[64*256];
  __shared__ float sc2a[128], sh2a[128];
  int tid = threadIdx.x;
  int lane = tid & 63, wvi = tid >> 6;
  int ct = blockIdx.x & 3;
  int rb = blockIdx.x >> 2;
  int c0 = ct * 64;
  int batch = rb >> 5;
  if (tid < 128){
    const float inv = 1.0f / (float)RC2;
    float mu = stats2a[tid] * inv;
    float var = fmaxf(stats2a[128+tid]*inv - mu*mu, 0.f);
    float s = rsqrtf(var + 1e-5f) * g2a[tid];
    sc2a[tid] = s; sh2a[tid] = be2a[tid] - mu*s;
  }
  {
    int cc = tid & 63, u0 = tid >> 6;
#pragma unroll
    for (int i = 0; i < 4; ++i){
      int u = u0 + i*4;
      unsigned short hb[8];
#pragma unroll
      for (int e = 0; e < 8; ++e) hb[e] = f2bf(W2b[(size_t)(u*8+e)*256 + c0 + cc]);
      *(short8*)(Btbs + cc*256 + u*16) = *(short8*)hb;
    }
  }
  __syncthreads();
  short8 bfrag[4];
#pragma unroll
  for (int kb4 = 0; kb4 < 4; ++kb4){
    int col_local = wvi*16 + (lane & 15);
    bfrag[kb4] = *(short8*)(Btbs + col_local*256 + kb4*64 + (lane>>4)*16);
  }
  float bb = b2b[c0 + wvi*16 + (lane & 15)];
  float vmn = INFINITY, vmx = -INFINITY, ssum = 0.f, ssq = 0.f;
  const unsigned short* y2u = (const unsigned short*)y2a;
  int sr = tid & 63, su = tid >> 6;
  for (int tile = 0; tile < 8; ++tile){
    int row0 = rb*512 + tile*64;
    if (tile > 0) __syncthreads();
#pragma unroll
    for (int i = 0; i < 4; ++i){
      int u = su + i*4;
      short8 v = *(const short8*)(y2u + (size_t)(row0 + sr)*128 + u*8);
      unsigned short ha[8];
#pragma unroll
      for (int e = 0; e < 8; ++e){
        int k = u*8 + e;
        float f = bf2f((unsigned short)v[e]);
        ha[e] = f2bf(silu_f(fmaf(f, sc2a[k], sh2a[k])));
      }
      *(short8*)(Albs + sr*256 + ((u*16) ^ ((sr & 7) << 4))) = *(short8*)ha;
    }
    __syncthreads();
#pragma unroll
    for (int sl = 0; sl < 4; ++sl){
      f32x4 acc = {0.f, 0.f, 0.f, 0.f};
#pragma unroll
      for (int kb4 = 0; kb4 < 4; ++kb4){
        int r = sl*16 + (lane & 15);
        short8 afrag = *(short8*)(Albs + r*256 + ((kb4*64 + (lane>>4)*16) ^ ((r & 7) << 4)));
        acc = __builtin_amdgcn_mfma_f32_16x16x32_bf16(afrag, bfrag[kb4], acc, 0, 0, 0);
      }
#pragma unroll
      for (int j = 0; j < 4; ++j){
        float y = acc[j] + bb;
        vmn = fminf(vmn, y); vmx = fmaxf(vmx, y);
        ssum += y; ssq = fmaf(y, y, ssq);
      }
    }
  }
#pragma unroll
  for (int off = 16; off <= 32; off += 16){
    vmn  = fminf(vmn,  __shfl_xor(vmn,  off));
    vmx  = fmaxf(vmx,  __shfl_xor(vmx,  off));
    ssum = ssum + __shfl_xor(ssum, off);
    ssq  = ssq  + __shfl_xor(ssq,  off);
  }
  if ((lane >> 4) == 0){
    int c = c0 + wvi*16 + lane;
    atomicAdd(&stats2b[c], ssum);
    atomicAdd(&stats2b[256+c], ssq);
    atomicMaxF(&gmax[batch*256 + c], vmx);
    atomicMinF(&gmin[batch*256 + c], vmn);
  }
}

__global__ __launch_bounds__(256) void final_kernel(
    const float* __restrict__ stats2b, const unsigned* __restrict__ gmax,
    const unsigned* __restrict__ gmin, const float* __restrict__ g2b,
    const float* __restrict__ be2b, float* __restrict__ out){
  int t = blockIdx.x*256 + threadIdx.x;
  if (t >= NB*256) return;
  int c = t & 255;
  const float inv = 1.0f / (float)RC2;
  float mu = stats2b[c]*inv;
  float var = fmaxf(stats2b[256+c]*inv - mu*mu, 0.f);
  float sc = rsqrtf(var + 1e-5f)*g2b[c];
  float sh = be2b[c] - mu*sc;
  float mx = __uint_as_float(gmax[t]);
  float mn = __uint_as_float(gmin[t]);
  out[t] = fmaxf(silu_f(fmaf(mx, sc, sh)), silu_f(fmaf(mn, sc, sh)));
}

extern "C" void kernel_launch(void* const* d_in, const int* in_sizes, int n_in,
                              void* d_out, int out_size, void* d_ws, size_t ws_size,
                              hipStream_t stream){
  (void)in_sizes; (void)n_in; (void)out_size; (void)ws_size;
  const float* pos  = (const float*)d_in[0];
  const float* W1   = (const float*)d_in[1];
  const float* b1   = (const float*)d_in[2];
  const float* g1   = (const float*)d_in[3];
  const float* be1  = (const float*)d_in[4];
  const float* W2a  = (const float*)d_in[5];
  const float* b2a  = (const float*)d_in[6];
  const float* g2a  = (const float*)d_in[7];
  const float* be2a = (const float*)d_in[8];
  const float* W2b  = (const float*)d_in[9];
  const float* b2b  = (const float*)d_in[10];
  const float* g2b  = (const float*)d_in[11];
  const float* be2b = (const float*)d_in[12];

  char* w = (char*)d_ws;
  size_t off = 0;
  auto carve = [&](size_t bytes)->void*{ void* p = w + off; off += (bytes + 255) & ~(size_t)255; return p; };
  int*      idx1    = (int*)carve((size_t)NB*NN*KNNK*4);      // 2 MB
  float*    h       = (float*)carve((size_t)NB*NN*64*4);      // 8 MB
  int*      idxf    = (int*)carve((size_t)NB*MM*4);
  float*    pos2    = (float*)carve((size_t)NB*MM*3*4);
  int*      idx2    = (int*)carve((size_t)NB*MM*KNNK*4);      // 1 MB
  float*    stats1  = (float*)carve(128*4);
  float*    stats2a = (float*)carve(256*4);
  float*    stats2b = (float*)carve(512*4);
  unsigned* gmax    = (unsigned*)carve(4096*4);
  unsigned* gmin    = (unsigned*)carve(4096*4);
  __hip_bfloat16* y2a = (__hip_bfloat16*)carve((size_t)RC2*128*2);  // 64 MB

  init_kernel<<<dim3(16), dim3(256), 0, stream>>>(stats1, stats2a, stats2b, gmax, gmin);
  k0_fps_knn1<<<dim3(272), dim3(256), 0, stream>>>(pos, idxf, pos2, idx1, W1, b1, stats1);
  k1_knn2_c1apply<<<dim3(1280), dim3(256), 0, stream>>>(pos2, idx2, pos, idx1, W1, b1, g1, be1, stats1, h);
  conv2a_kernel<<<dim3(1024), dim3(256), 0, stream>>>(h, idxf, pos2, idx2, W2a, b2a, stats2a, y2a);
  conv2b_kernel<<<dim3(2048), dim3(256), 0, stream>>>(y2a, stats2a, g2a, be2a, W2b, b2b, stats2b, gmax, gmin);
  final_kernel<<<dim3(16), dim3(256), 0, stream>>>(stats2b, gmax, gmin, g2b, be2b, (float*)d_out);
}

// Round 12
// 825.103 us; speedup vs baseline: 2.1114x; 1.1433x over previous
//
#include <hip/hip_runtime.h>
#include <hip/hip_bf16.h>

#define NB 16
#define NN 2048
#define KNNK 16
#define MM 1024
#define RC1 (NB*NN*KNNK)   // 524288 conv1 BN rows
#define RC2 (NB*MM*KNNK)   // 262144 conv2 BN rows

typedef unsigned long long u64;
typedef __attribute__((ext_vector_type(8))) short short8;
typedef __attribute__((ext_vector_type(4))) float f32x4;

__device__ __forceinline__ float frn_mul(float a, float b){ return __fmul_rn(a,b); }
__device__ __forceinline__ float frn_add(float a, float b){ return __fadd_rn(a,b); }
__device__ __forceinline__ float frn_sub(float a, float b){ return __fsub_rn(a,b); }
__device__ __forceinline__ float silu_f(float x){ return x / (1.0f + __expf(-x)); }
__device__ __forceinline__ u64 umax64(u64 a, u64 b){ return a > b ? a : b; }

__device__ __forceinline__ unsigned f32_sortable(float f){
  unsigned u = __float_as_uint(f);
  return u ^ ((unsigned)((int)u >> 31) | 0x80000000u);
}
__device__ __forceinline__ unsigned short f2bf(float f){
  unsigned u = __float_as_uint(f);
  return (unsigned short)((u + 0x7FFFu + ((u >> 16) & 1u)) >> 16);
}
__device__ __forceinline__ float bf2f(unsigned short h){
  return __uint_as_float(((unsigned)h) << 16);
}

__device__ __forceinline__ void atomicMaxF(unsigned* addr, float v){
  if (v >= 0.f) atomicMax((int*)addr, (int)__float_as_uint(v));
  else          atomicMin(addr, __float_as_uint(v));
}
__device__ __forceinline__ void atomicMinF(unsigned* addr, float v){
  if (v >= 0.f) atomicMin((int*)addr, (int)__float_as_uint(v));
  else          atomicMax(addr, __float_as_uint(v));
}

__global__ __launch_bounds__(256) void init_kernel(float* stats1, float* stats2a, float* stats2b,
                                                   unsigned* gmax, unsigned* gmin){
  int t = blockIdx.x*256 + threadIdx.x;
  if (t < 128) stats1[t] = 0.f;
  if (t < 256) stats2a[t] = 0.f;
  if (t < 512) stats2b[t] = 0.f;
  if (t < 4096){ gmax[t] = 0xFF800000u; gmin[t] = 0x7F800000u; }
}

// insertion scan over [jbase, jbase+CNT) LDS points; best[] sorted ascending
template<int CNT>
__device__ __forceinline__ void knn_scan(const float4* pts, int jbase,
                                         float xi, float yi, float zi, float n2i, u64* best){
#pragma unroll
  for (int p = 0; p < KNNK; ++p) best[p] = ~0ull;
  for (int jj = 0; jj < CNT; ++jj){
    float4 v = pts[jbase + jj];
    float e = frn_add(frn_add(frn_mul(xi,v.x), frn_mul(yi,v.y)), frn_mul(zi,v.z));
    float d = frn_sub(frn_add(n2i, v.w), frn_mul(2.0f, e));
    u64 key = ((u64)f32_sortable(d) << 32) | (unsigned)(jbase + jj);
    if (key < best[KNNK-1]){
      u64 cur = key;
#pragma unroll
      for (int p = 0; p < KNNK; ++p){
        u64 mn = best[p] < cur ? best[p] : cur;
        u64 mx = best[p] < cur ? cur : best[p];
        best[p] = mn; cur = mx;
      }
    }
  }
}

// ---- K0: blocks 0..15 = FPS (r7 verbatim); blocks 16..271 = knn1 chunk scan +
//      in-block merge + conv1 stats. cres/idxl padded to stride 17 (bank fix). ----
__global__ __launch_bounds__(256) void k0_fps_knn1(const float* __restrict__ pos,
    int* __restrict__ idxf, float* __restrict__ pos2, int* __restrict__ idx1,
    const float* __restrict__ W1, const float* __restrict__ b1, float* __restrict__ stats1){
  __shared__ __align__(16) char smem[77*1024];
  int tid = threadIdx.x;
  if (blockIdx.x < 16){
    int b = blockIdx.x;
    float4* pts4 = (float4*)smem;                    // 2048 * 16B = 32 KB
    int* sel = (int*)(smem + 32*1024);               // 1024 ints
    u64* wred = (u64*)(smem + 36*1024);              // [2][4]
    const float* pb = pos + (size_t)b*NN*3;
    float X[8], Y[8], Z[8], MD[8];
    unsigned LO[8];
#pragma unroll
    for (int q = 0; q < 8; ++q){
      int p = tid + 256*q;
      float x = pb[p*3+0], y = pb[p*3+1], z = pb[p*3+2];
      X[q] = x; Y[q] = y; Z[q] = z;
      LO[q] = ~(unsigned)p;
      pts4[p] = make_float4(x, y, z, 0.f);
    }
    float qx = pb[0], qy = pb[1], qz = pb[2];
#pragma unroll
    for (int q = 0; q < 8; ++q){
      float dx = frn_sub(X[q],qx), dy = frn_sub(Y[q],qy), dz = frn_sub(Z[q],qz);
      MD[q] = frn_add(frn_add(frn_mul(dx,dx), frn_mul(dy,dy)), frn_mul(dz,dz));
    }
    if (tid == 0) sel[0] = 0;
    int wv = tid >> 6;
    __syncthreads();
    for (int s = 1; s < MM; ++s){
      u64 t0 = umax64(((u64)__float_as_uint(MD[0])<<32)|LO[0], ((u64)__float_as_uint(MD[1])<<32)|LO[1]);
      u64 t1 = umax64(((u64)__float_as_uint(MD[2])<<32)|LO[2], ((u64)__float_as_uint(MD[3])<<32)|LO[3]);
      u64 t2 = umax64(((u64)__float_as_uint(MD[4])<<32)|LO[4], ((u64)__float_as_uint(MD[5])<<32)|LO[5]);
      u64 t3 = umax64(((u64)__float_as_uint(MD[6])<<32)|LO[6], ((u64)__float_as_uint(MD[7])<<32)|LO[7]);
      u64 kk = umax64(umax64(t0, t1), umax64(t2, t3));
#define RED_DPP(CTRL) { \
      unsigned lo_ = (unsigned)kk, hi_ = (unsigned)(kk>>32); \
      unsigned plo = (unsigned)__builtin_amdgcn_update_dpp((int)lo_,(int)lo_,CTRL,0xF,0xF,false); \
      unsigned phi = (unsigned)__builtin_amdgcn_update_dpp((int)hi_,(int)hi_,CTRL,0xF,0xF,false); \
      u64 o = ((u64)phi<<32)|plo; kk = o > kk ? o : kk; }
      RED_DPP(0xB1)
      RED_DPP(0x4E)
      RED_DPP(0x124)
      RED_DPP(0x128)
      RED_DPP(0x142)
      RED_DPP(0x143)
#undef RED_DPP
      int par = s & 1;
      if ((tid & 63) == 63) wred[par*4 + wv] = kk;
      __syncthreads();
      const u64* wr = wred + par*4;
      u64 K = umax64(umax64(wr[0], wr[1]), umax64(wr[2], wr[3]));
      unsigned wp = ~(unsigned)K;
      if (tid == 0) sel[s] = (int)wp;
      float4 wc = pts4[wp];
#pragma unroll
      for (int q = 0; q < 8; ++q){
        float dx = frn_sub(X[q],wc.x), dy = frn_sub(Y[q],wc.y), dz = frn_sub(Z[q],wc.z);
        float d = frn_add(frn_add(frn_mul(dx,dx), frn_mul(dy,dy)), frn_mul(dz,dz));
        MD[q] = fminf(MD[q], d);
      }
    }
    __syncthreads();
    for (int m = tid; m < MM; m += 256){
      int j = sel[m];
      idxf[b*MM + m] = j;
      float4 c = pts4[j];
      pos2[(size_t)(b*MM+m)*3+0] = c.x;
      pos2[(size_t)(b*MM+m)*3+1] = c.y;
      pos2[(size_t)(b*MM+m)*3+2] = c.z;
    }
  } else {
    int cid = blockIdx.x - 16;           // 0..255
    int b = cid >> 4;
    int rb16 = cid & 15;                 // 128-row group
    float4* pts4 = (float4*)smem;        // 32 KB (x,y,z,n2)
    u64* cres = (u64*)(smem + 32*1024);  // 256 threads * 17 keys = 34816 B
    int* idxl = (int*)(smem + 32*1024 + 34816);      // 128 * 17 ints = 8704 B
    float* red = (float*)(smem + 32*1024 + 34816 + 8704); // 4*64*2 = 2 KB
    const float* pb = pos + (size_t)b*NN*3;
    for (int i = tid; i < NN; i += 256){
      float x = pb[i*3+0], y = pb[i*3+1], z = pb[i*3+2];
      float n2 = frn_add(frn_add(frn_mul(x,x), frn_mul(y,y)), frn_mul(z,z));
      pts4[i] = make_float4(x, y, z, n2);
    }
    __syncthreads();
    int lrow = tid & 127;
    int ch = tid >> 7;                   // chunk 0 or 1
    int i = rb16*128 + lrow;
    float4 qv = pts4[i];
    u64 best[KNNK];
    knn_scan<1024>(pts4, ch*1024, qv.x, qv.y, qv.z, qv.w, best);
#pragma unroll
    for (int p = 0; p < KNNK; ++p) cres[tid*17 + p] = best[p];
    __syncthreads();
    if (tid < 128){
      const u64* A = cres + tid*17;
      const u64* B = cres + (tid + 128)*17;
      int ia = 0, ib = 0;
      int* op = idx1 + ((size_t)(b*NN + rb16*128 + tid))*KNNK;
#pragma unroll
      for (int p = 0; p < KNNK; ++p){
        u64 ka = A[ia], kb = B[ib];
        int v;
        if (ka < kb){ v = (int)(unsigned)ka; ++ia; }
        else        { v = (int)(unsigned)kb; ++ib; }
        op[p] = v;
        idxl[tid*17 + p] = v;
      }
    }
    __syncthreads();
    int lane = tid & 63, wv = tid >> 6;
    float w[6];
#pragma unroll
    for (int f = 0; f < 6; ++f) w[f] = W1[f*64 + lane];
    float bias = b1[lane];
    float ssum = 0.f, ssq = 0.f;
    for (int r = 0; r < 32; ++r){
      int lr = wv*32 + r;
      float4 pi = pts4[rb16*128 + lr];
      const int* ip = idxl + lr*17;
#pragma unroll 4
      for (int k = 0; k < KNNK; ++k){
        int j = ip[k];
        float4 pj = pts4[j];
        float y = bias;
        y = fmaf(pj.x, w[0], y); y = fmaf(pj.y, w[1], y); y = fmaf(pj.z, w[2], y);
        y = fmaf(pj.x - pi.x, w[3], y); y = fmaf(pj.y - pi.y, w[4], y); y = fmaf(pj.z - pi.z, w[5], y);
        ssum += y; ssq = fmaf(y, y, ssq);
      }
    }
    red[(wv*64+lane)*2+0] = ssum; red[(wv*64+lane)*2+1] = ssq;
    __syncthreads();
    if (tid < 64){
      float s = red[(0*64+lane)*2]+red[(1*64+lane)*2]+red[(2*64+lane)*2]+red[(3*64+lane)*2];
      float q = red[(0*64+lane)*2+1]+red[(1*64+lane)*2+1]+red[(2*64+lane)*2+1]+red[(3*64+lane)*2+1];
      atomicAdd(&stats1[lane], s);
      atomicAdd(&stats1[64+lane], q);
    }
  }
}

// ---- K1: blocks 0..255 = knn2 (4 chunks + in-block merge), 256..1279 = conv1 apply (h -> bf16) ----
__global__ __launch_bounds__(256) void k1_knn2_c1apply(
    const float* __restrict__ pos2, int* __restrict__ idx2,
    const float* __restrict__ pos, const int* __restrict__ idx1,
    const float* __restrict__ W1, const float* __restrict__ b1,
    const float* __restrict__ g1, const float* __restrict__ be1,
    const float* __restrict__ stats1, unsigned short* __restrict__ hbf){
  __shared__ __align__(16) char smem[48*1024];
  int tid = threadIdx.x;
  if (blockIdx.x < 256){
    int b = blockIdx.x >> 4;
    int rb = blockIdx.x & 15;            // 64-row group
    float4* sm = (float4*)smem;          // 1024 * 16B = 16 KB
    u64* cres = (u64*)(smem + 16*1024);  // 256 * 16 * 8 = 32 KB
    const float* pb = pos2 + (size_t)b*MM*3;
    for (int t = tid; t < MM; t += 256){
      float x = pb[t*3+0], y = pb[t*3+1], z = pb[t*3+2];
      float n2 = frn_add(frn_add(frn_mul(x,x), frn_mul(y,y)), frn_mul(z,z));
      sm[t] = make_float4(x, y, z, n2);
    }
    __syncthreads();
    int trow = tid & 63, ch = tid >> 6;  // 4 chunks of 256
    int i = rb*64 + trow;
    float4 qv = sm[i];
    u64 best[KNNK];
    knn_scan<256>(sm, ch*256, qv.x, qv.y, qv.z, qv.w, best);
#pragma unroll
    for (int p = 0; p < KNNK; ++p) cres[tid*KNNK + p] = best[p];
    __syncthreads();
    if (tid < 64){
      const u64* L0 = cres + tid*KNNK;
      const u64* L1 = cres + (64 + tid)*KNNK;
      const u64* L2 = cres + (128 + tid)*KNNK;
      const u64* L3 = cres + (192 + tid)*KNNK;
      int o0=0, o1=0, o2=0, o3=0;
      int* op = idx2 + ((size_t)(b*MM + rb*64 + tid))*KNNK;
#pragma unroll
      for (int p = 0; p < KNNK; ++p){
        u64 k0 = L0[o0], k1 = L1[o1], k2 = L2[o2], k3 = L3[o3];
        u64 m01 = k0 < k1 ? k0 : k1;
        u64 m23 = k2 < k3 ? k2 : k3;
        u64 m = m01 < m23 ? m01 : m23;
        op[p] = (int)(unsigned)m;
        o0 += (m == k0); o1 += (m == k1); o2 += (m == k2); o3 += (m == k3);
      }
    }
  } else {
    int lane = tid & 63, wv = tid >> 6;
    int wave = (blockIdx.x - 256)*4 + wv;
    float w[6];
#pragma unroll
    for (int f = 0; f < 6; ++f) w[f] = W1[f*64 + lane];
    float bias = b1[lane];
    const float inv = 1.0f / (float)RC1;
    float mu = stats1[lane] * inv;
    float var = fmaxf(stats1[64+lane]*inv - mu*mu, 0.f);
    float sc = rsqrtf(var + 1e-5f) * g1[lane];
    float sh = be1[lane] - mu*sc;
    for (int r = 0; r < 8; ++r){
      int row = wave*8 + r;
      int b = row >> 11, ii = row & 2047;
      const float* pi = pos + ((size_t)(b*NN + ii))*3;
      float xi = pi[0], yi = pi[1], zi = pi[2];
      const int* ip = idx1 + (size_t)row * KNNK;
      float ymn = INFINITY, ymx = -INFINITY;
#pragma unroll 4
      for (int k = 0; k < KNNK; ++k){
        int j = ip[k];
        const float* pj = pos + ((size_t)(b*NN + j))*3;
        float xj = pj[0], yj = pj[1], zj = pj[2];
        float y = bias;
        y = fmaf(xj, w[0], y); y = fmaf(yj, w[1], y); y = fmaf(zj, w[2], y);
        y = fmaf(xj - xi, w[3], y); y = fmaf(yj - yi, w[4], y); y = fmaf(zj - zi, w[5], y);
        ymn = fminf(ymn, y); ymx = fmaxf(ymx, y);
      }
      hbf[((size_t)row << 6) + lane] = f2bf(fmaxf(silu_f(fmaf(ymx, sc, sh)), silu_f(fmaf(ymn, sc, sh))));
    }
  }
}

// ---- conv2a: MFMA 16x16x32 bf16. 64-row tiles, K padded 67->96 (zero rows).
//      A staged bf16 in LDS (row stride 104 bf16 = 208B, 2-way bank = free);
//      W2a^T staged bf16 once; stats in-lane (col fixed per lane). ----
__global__ __launch_bounds__(256) void conv2a_kernel(
    const unsigned short* __restrict__ hbf, const int* __restrict__ idxf,
    const float* __restrict__ pos2, const int* __restrict__ idx2,
    const float* __restrict__ W2a, const float* __restrict__ b2a,
    float* __restrict__ stats2a, __hip_bfloat16* __restrict__ y2a){
  __shared__ __align__(16) unsigned short At[64*104];   // 13.3 KB
  __shared__ __align__(16) unsigned short Wt[128*104];  // 26.6 KB (W2a^T)
  __shared__ int qs[64];
  int tid = threadIdx.x;
  int lane = tid & 63, wvi = tid >> 6;
  for (int i = tid; i < 96*128; i += 256){
    int k = i >> 7, c = i & 127;
    Wt[c*104 + k] = (k < 67) ? f2bf(W2a[k*128 + c]) : (unsigned short)0;
  }
  for (int i = tid; i < 64*104/2; i += 256) ((unsigned*)At)[i] = 0u;
  __syncthreads();
  int cb = wvi*32;
  short8 bfrag[2][3];
#pragma unroll
  for (int cf = 0; cf < 2; ++cf)
#pragma unroll
    for (int kf = 0; kf < 3; ++kf){
      int col = cb + cf*16 + (lane & 15);
      bfrag[cf][kf] = *(short8*)(Wt + col*104 + kf*32 + (lane>>4)*8);
    }
  float bb[2] = { b2a[cb + (lane & 15)], b2a[cb + 16 + (lane & 15)] };
  float ssum[2] = {0.f, 0.f}, ssq[2] = {0.f, 0.f};
  for (int t = 0; t < 4; ++t){
    int tbase = (blockIdx.x*4 + t)*64;
    if (t > 0) __syncthreads();
    if (tid < 64){
      int grow = tbase + tid;
      int b = grow >> 14;
      int m = (grow >> 4) & 1023;
      int j = idx2[grow];
      int q = idxf[b*MM + j];
      qs[tid] = b*NN + q;
      const float* pm = pos2 + ((size_t)(b*MM + m))*3;
      const float* pj = pos2 + ((size_t)(b*MM + j))*3;
      At[tid*104 + 64] = f2bf(pj[0]-pm[0]);
      At[tid*104 + 65] = f2bf(pj[1]-pm[1]);
      At[tid*104 + 66] = f2bf(pj[2]-pm[2]);
    }
    __syncthreads();
    {
      int r = tid & 63, ck = tid >> 6;
      const unsigned short* src = hbf + (size_t)qs[r]*64 + ck*16;
      short8 v0 = *(const short8*)(src);
      short8 v1 = *(const short8*)(src + 8);
      *(short8*)(At + r*104 + ck*16) = v0;
      *(short8*)(At + r*104 + ck*16 + 8) = v1;
    }
    __syncthreads();
#pragma unroll
    for (int rf = 0; rf < 4; ++rf){
      int r = rf*16 + (lane & 15);
      short8 af[3];
#pragma unroll
      for (int kf = 0; kf < 3; ++kf)
        af[kf] = *(short8*)(At + r*104 + kf*32 + (lane>>4)*8);
#pragma unroll
      for (int cf = 0; cf < 2; ++cf){
        f32x4 acc = {0.f,0.f,0.f,0.f};
#pragma unroll
        for (int kf = 0; kf < 3; ++kf)
          acc = __builtin_amdgcn_mfma_f32_16x16x32_bf16(af[kf], bfrag[cf][kf], acc, 0, 0, 0);
#pragma unroll
        for (int jj = 0; jj < 4; ++jj){
          int row = tbase + rf*16 + (lane>>4)*4 + jj;
          int col = cb + cf*16 + (lane & 15);
          float y = acc[jj] + bb[cf];
          ssum[cf] += y; ssq[cf] = fmaf(y, y, ssq[cf]);
          y2a[(size_t)row*128 + col] = __float2bfloat16(y);
        }
      }
    }
  }
#pragma unroll
  for (int cf = 0; cf < 2; ++cf){
#pragma unroll
    for (int off = 16; off <= 32; off += 16){
      ssum[cf] += __shfl_xor(ssum[cf], off);
      ssq[cf]  += __shfl_xor(ssq[cf],  off);
    }
  }
  if ((lane >> 4) == 0){
    atomicAdd(&stats2a[cb + lane], ssum[0]);
    atomicAdd(&stats2a[128 + cb + lane], ssq[0]);
    atomicAdd(&stats2a[cb + 16 + lane], ssum[1]);
    atomicAdd(&stats2a[128 + cb + 16 + lane], ssq[1]);
  }
}

// ---- conv2b: MFMA 16x16x32 bf16 (r7 verbatim) ----
__global__ __launch_bounds__(256) void conv2b_kernel(
    const __hip_bfloat16* __restrict__ y2a, const float* __restrict__ stats2a,
    const float* __restrict__ g2a, const float* __restrict__ be2a,
    const float* __restrict__ W2b, const float* __restrict__ b2b,
    float* __restrict__ stats2b, unsigned* __restrict__ gmax, unsigned* __restrict__ gmin){
  __shared__ __align__(16) char Albs[64*256];
  __shared__ __align__(16) char Btbs[64*256];
  __shared__ float sc2a[128], sh2a[128];
  int tid = threadIdx.x;
  int lane = tid & 63, wvi = tid >> 6;
  int ct = blockIdx.x & 3;
  int rb = blockIdx.x >> 2;
  int c0 = ct * 64;
  int batch = rb >> 5;
  if (tid < 128){
    const float inv = 1.0f / (float)RC2;
    float mu = stats2a[tid] * inv;
    float var = fmaxf(stats2a[128+tid]*inv - mu*mu, 0.f);
    float s = rsqrtf(var + 1e-5f) * g2a[tid];
    sc2a[tid] = s; sh2a[tid] = be2a[tid] - mu*s;
  }
  {
    int cc = tid & 63, u0 = tid >> 6;
#pragma unroll
    for (int i = 0; i < 4; ++i){
      int u = u0 + i*4;
      unsigned short hb[8];
#pragma unroll
      for (int e = 0; e < 8; ++e) hb[e] = f2bf(W2b[(size_t)(u*8+e)*256 + c0 + cc]);
      *(short8*)(Btbs + cc*256 + u*16) = *(short8*)hb;
    }
  }
  __syncthreads();
  short8 bfrag[4];
#pragma unroll
  for (int kb4 = 0; kb4 < 4; ++kb4){
    int col_local = wvi*16 + (lane & 15);
    bfrag[kb4] = *(short8*)(Btbs + col_local*256 + kb4*64 + (lane>>4)*16);
  }
  float bb = b2b[c0 + wvi*16 + (lane & 15)];
  float vmn = INFINITY, vmx = -INFINITY, ssum = 0.f, ssq = 0.f;
  const unsigned short* y2u = (const unsigned short*)y2a;
  int sr = tid & 63, su = tid >> 6;
  for (int tile = 0; tile < 8; ++tile){
    int row0 = rb*512 + tile*64;
    if (tile > 0) __syncthreads();
#pragma unroll
    for (int i = 0; i < 4; ++i){
      int u = su + i*4;
      short8 v = *(const short8*)(y2u + (size_t)(row0 + sr)*128 + u*8);
      unsigned short ha[8];
#pragma unroll
      for (int e = 0; e < 8; ++e){
        int k = u*8 + e;
        float f = bf2f((unsigned short)v[e]);
        ha[e] = f2bf(silu_f(fmaf(f, sc2a[k], sh2a[k])));
      }
      *(short8*)(Albs + sr*256 + ((u*16) ^ ((sr & 7) << 4))) = *(short8*)ha;
    }
    __syncthreads();
#pragma unroll
    for (int sl = 0; sl < 4; ++sl){
      f32x4 acc = {0.f, 0.f, 0.f, 0.f};
#pragma unroll
      for (int kb4 = 0; kb4 < 4; ++kb4){
        int r = sl*16 + (lane & 15);
        short8 afrag = *(short8*)(Albs + r*256 + ((kb4*64 + (lane>>4)*16) ^ ((r & 7) << 4)));
        acc = __builtin_amdgcn_mfma_f32_16x16x32_bf16(afrag, bfrag[kb4], acc, 0, 0, 0);
      }
#pragma unroll
      for (int j = 0; j < 4; ++j){
        float y = acc[j] + bb;
        vmn = fminf(vmn, y); vmx = fmaxf(vmx, y);
        ssum += y; ssq = fmaf(y, y, ssq);
      }
    }
  }
#pragma unroll
  for (int off = 16; off <= 32; off += 16){
    vmn  = fminf(vmn,  __shfl_xor(vmn,  off));
    vmx  = fmaxf(vmx,  __shfl_xor(vmx,  off));
    ssum = ssum + __shfl_xor(ssum, off);
    ssq  = ssq  + __shfl_xor(ssq,  off);
  }
  if ((lane >> 4) == 0){
    int c = c0 + wvi*16 + lane;
    atomicAdd(&stats2b[c], ssum);
    atomicAdd(&stats2b[256+c], ssq);
    atomicMaxF(&gmax[batch*256 + c], vmx);
    atomicMinF(&gmin[batch*256 + c], vmn);
  }
}

__global__ __launch_bounds__(256) void final_kernel(
    const float* __restrict__ stats2b, const unsigned* __restrict__ gmax,
    const unsigned* __restrict__ gmin, const float* __restrict__ g2b,
    const float* __restrict__ be2b, float* __restrict__ out){
  int t = blockIdx.x*256 + threadIdx.x;
  if (t >= NB*256) return;
  int c = t & 255;
  const float inv = 1.0f / (float)RC2;
  float mu = stats2b[c]*inv;
  float var = fmaxf(stats2b[256+c]*inv - mu*mu, 0.f);
  float sc = rsqrtf(var + 1e-5f)*g2b[c];
  float sh = be2b[c] - mu*sc;
  float mx = __uint_as_float(gmax[t]);
  float mn = __uint_as_float(gmin[t]);
  out[t] = fmaxf(silu_f(fmaf(mx, sc, sh)), silu_f(fmaf(mn, sc, sh)));
}

extern "C" void kernel_launch(void* const* d_in, const int* in_sizes, int n_in,
                              void* d_out, int out_size, void* d_ws, size_t ws_size,
                              hipStream_t stream){
  (void)in_sizes; (void)n_in; (void)out_size; (void)ws_size;
  const float* pos  = (const float*)d_in[0];
  const float* W1   = (const float*)d_in[1];
  const float* b1   = (const float*)d_in[2];
  const float* g1   = (const float*)d_in[3];
  const float* be1  = (const float*)d_in[4];
  const float* W2a  = (const float*)d_in[5];
  const float* b2a  = (const float*)d_in[6];
  const float* g2a  = (const float*)d_in[7];
  const float* be2a = (const float*)d_in[8];
  const float* W2b  = (const float*)d_in[9];
  const float* b2b  = (const float*)d_in[10];
  const float* g2b  = (const float*)d_in[11];
  const float* be2b = (const float*)d_in[12];

  char* w = (char*)d_ws;
  size_t off = 0;
  auto carve = [&](size_t bytes)->void*{ void* p = w + off; off += (bytes + 255) & ~(size_t)255; return p; };
  int*      idx1    = (int*)carve((size_t)NB*NN*KNNK*4);      // 2 MB
  unsigned short* hbf = (unsigned short*)carve((size_t)NB*NN*64*2);  // 4 MB (bf16)
  int*      idxf    = (int*)carve((size_t)NB*MM*4);
  float*    pos2    = (float*)carve((size_t)NB*MM*3*4);
  int*      idx2    = (int*)carve((size_t)NB*MM*KNNK*4);      // 1 MB
  float*    stats1  = (float*)carve(128*4);
  float*    stats2a = (float*)carve(256*4);
  float*    stats2b = (float*)carve(512*4);
  unsigned* gmax    = (unsigned*)carve(4096*4);
  unsigned* gmin    = (unsigned*)carve(4096*4);
  __hip_bfloat16* y2a = (__hip_bfloat16*)carve((size_t)RC2*128*2);  // 64 MB

  init_kernel<<<dim3(16), dim3(256), 0, stream>>>(stats1, stats2a, stats2b, gmax, gmin);
  k0_fps_knn1<<<dim3(272), dim3(256), 0, stream>>>(pos, idxf, pos2, idx1, W1, b1, stats1);
  k1_knn2_c1apply<<<dim3(1280), dim3(256), 0, stream>>>(pos2, idx2, pos, idx1, W1, b1, g1, be1, stats1, hbf);
  conv2a_kernel<<<dim3(1024), dim3(256), 0, stream>>>(hbf, idxf, pos2, idx2, W2a, b2a, stats2a, y2a);
  conv2b_kernel<<<dim3(2048), dim3(256), 0, stream>>>(y2a, stats2a, g2a, be2a, W2b, b2b, stats2b, gmax, gmin);
  final_kernel<<<dim3(16), dim3(256), 0, stream>>>(stats2b, gmax, gmin, g2b, be2b, (float*)d_out);
}